// Round 16
// baseline (189.091 us; speedup 1.0000x reference)
//
#include <hip/hip_runtime.h>
#include <hip/hip_bf16.h>

// GCNConv: coarse bin (64 tgts/bucket) -> fused per-half-bucket {LDS counting
// sort + per-node oct-lane gather + epilogue}. No fp32 global atomics.
// agg[c] = dinv[c] * ( xs[c] + sum_{e: col[e]==c} xs[row[e]] ),
//   xs[i] = (x@W)[i] * dinv[i],  dinv[i] = rsqrt(1 + indeg(i))
// out = dropout(tanh(agg + b)), JAX partitionable-threefry key (0,42), p_keep=0.9:
//   bits[p] = o0^o1 of threefry((0,42), 0, p); u = bitcast(bits>>9|0x3f800000)-1; keep = u<0.9.
//
// R8: __shfl only in uniform regions (predicated regions contain loads only).
// R15 lesson: k_sagg is L2-miss MLP-bound (85MB fill @1.4TB/s; 12.8MB table >
//   4MB/XCD L2). R16: uint4 oct-lanes — 1 wave-load = 8 edges = 16 lines in
//   flight; 2 loads/iter = 2x MLP. k_deg folded into k_bhist (global deg[]).
//
// ws (19.6 MB): deg i32[NN] | bhist i32[NBUCK] | xsh bf16[NN*64] |
//               packed u32[NE] | bstart i32[NBUCK+1] | bcur i32[NBUCK]

#define NN 100000
#define NE 1600000
#define NBUCK 1563
#define P1B 128
#define P1T 1024
#define CHUNK 12500         // P1B * CHUNK == NE
#define HCAP 1536           // per-half-bucket LDS sort capacity (mean 512)

// ---------------- Threefry2x32 (JAX-exact) ----------------
__device__ __forceinline__ unsigned rotl32(unsigned x, int r) {
    return (x << r) | (x >> (32 - r));
}

__device__ __forceinline__ void threefry2x32(unsigned k0, unsigned k1,
                                             unsigned x0, unsigned x1,
                                             unsigned& o0, unsigned& o1) {
    const unsigned ks0 = k0, ks1 = k1, ks2 = k0 ^ k1 ^ 0x1BD11BDAu;
    x0 += ks0; x1 += ks1;
    x0 += x1; x1 = rotl32(x1, 13); x1 ^= x0;
    x0 += x1; x1 = rotl32(x1, 15); x1 ^= x0;
    x0 += x1; x1 = rotl32(x1, 26); x1 ^= x0;
    x0 += x1; x1 = rotl32(x1, 6);  x1 ^= x0;
    x0 += ks1; x1 += ks2 + 1u;
    x0 += x1; x1 = rotl32(x1, 17); x1 ^= x0;
    x0 += x1; x1 = rotl32(x1, 29); x1 ^= x0;
    x0 += x1; x1 = rotl32(x1, 16); x1 ^= x0;
    x0 += x1; x1 = rotl32(x1, 24); x1 ^= x0;
    x0 += ks2; x1 += ks0 + 2u;
    x0 += x1; x1 = rotl32(x1, 13); x1 ^= x0;
    x0 += x1; x1 = rotl32(x1, 15); x1 ^= x0;
    x0 += x1; x1 = rotl32(x1, 26); x1 ^= x0;
    x0 += x1; x1 = rotl32(x1, 6);  x1 ^= x0;
    x0 += ks0; x1 += ks1 + 3u;
    x0 += x1; x1 = rotl32(x1, 17); x1 ^= x0;
    x0 += x1; x1 = rotl32(x1, 29); x1 ^= x0;
    x0 += x1; x1 = rotl32(x1, 16); x1 ^= x0;
    x0 += x1; x1 = rotl32(x1, 24); x1 ^= x0;
    x0 += ks1; x1 += ks2 + 4u;
    x0 += x1; x1 = rotl32(x1, 13); x1 ^= x0;
    x0 += x1; x1 = rotl32(x1, 15); x1 ^= x0;
    x0 += x1; x1 = rotl32(x1, 26); x1 ^= x0;
    x0 += x1; x1 = rotl32(x1, 6);  x1 ^= x0;
    x0 += ks2; x1 += ks0 + 5u;
    o0 = x0; o1 = x1;
}

// ---------------- Kernels ----------------
// Bucket histogram + per-node degree (global atomics, L2-resident).
__global__ __launch_bounds__(P1T) void k_bhist(const int* __restrict__ ei,
                                               int* __restrict__ bhist,
                                               int* __restrict__ deg) {
    __shared__ int h[NBUCK];
    const int tid = threadIdx.x;
    for (int i = tid; i < NBUCK; i += P1T) h[i] = 0;
    __syncthreads();
    const int base = blockIdx.x * CHUNK;
    for (int i = tid; i < CHUNK; i += P1T) {
        const unsigned t = (unsigned)ei[NE + base + i];
        if (t < NN) {
            atomicAdd(&h[t >> 6], 1);
            atomicAdd(&deg[t], 1);
        }
    }
    __syncthreads();
    for (int i = tid; i < NBUCK; i += P1T) {
        const int v = h[i];
        if (v) atomicAdd(&bhist[i], v);
    }
}

__global__ __launch_bounds__(1024) void k_bscan(const int* __restrict__ bhist,
                                                int* __restrict__ bstart,
                                                int* __restrict__ bcur) {
    __shared__ int s[2048];
    const int t = threadIdx.x;
    const int i0 = t, i1 = t + 1024;
    const int c0 = (i0 < NBUCK) ? bhist[i0] : 0;
    const int c1 = (i1 < NBUCK) ? bhist[i1] : 0;
    s[i0] = c0; s[i1] = c1;
    __syncthreads();
    for (int d = 1; d < 2048; d <<= 1) {
        const int a0 = (i0 >= d) ? s[i0 - d] : 0;
        const int a1 = (i1 >= d) ? s[i1 - d] : 0;
        __syncthreads();
        s[i0] += a0; s[i1] += a1;
        __syncthreads();
    }
    if (i0 < NBUCK) { const int b = s[i0] - c0; bstart[i0] = b; bcur[i0] = b; }
    if (i1 < NBUCK) { const int b = s[i1] - c1; bstart[i1] = b; bcur[i1] = b; }
    if (t == 0) bstart[NBUCK] = NE;
}

__global__ __launch_bounds__(P1T) void k_p1(const int* __restrict__ ei,
                                            int* __restrict__ bcur,
                                            unsigned* __restrict__ packed) {
    __shared__ int hb[NBUCK];
    __shared__ int lc[NBUCK];
    const int tid = threadIdx.x;
    for (int i = tid; i < NBUCK; i += P1T) { hb[i] = 0; lc[i] = 0; }
    __syncthreads();
    const int base = blockIdx.x * CHUNK;
    for (int i = tid; i < CHUNK; i += P1T) {
        const unsigned t = (unsigned)ei[NE + base + i];
        if (t < NN) atomicAdd(&hb[t >> 6], 1);
    }
    __syncthreads();
    for (int i = tid; i < NBUCK; i += P1T) {
        const int h = hb[i];
        hb[i] = h ? atomicAdd(&bcur[i], h) : 0;
    }
    __syncthreads();
    for (int i = tid; i < CHUNK; i += P1T) {
        const unsigned t = (unsigned)ei[NE + base + i];
        if (t >= NN) continue;
        const unsigned src = (unsigned)ei[base + i];
        const int bk = t >> 6;
        const unsigned pos = (unsigned)(hb[bk] + atomicAdd(&lc[bk], 1));
        if (pos < NE) packed[pos] = src | ((t & 63u) << 17);
    }
}

// x@W: W register-resident, x rows staged in LDS, distributed per-row via
// ds_read_b128 broadcasts + 64 register FMAs; dinv computed inline from deg.
__global__ __launch_bounds__(256) void k_xw(const float* __restrict__ x,
                                            const float* __restrict__ W,
                                            const int* __restrict__ deg,
                                            __hip_bfloat16* __restrict__ xsh) {
    __shared__ float Wl[64 * 64];   // 16 KB
    __shared__ float xl[64 * 64];   // 16 KB
    const int tid = threadIdx.x;
    for (int i = tid; i < 64 * 64; i += 256) Wl[i] = W[i];  // coalesced
    const int row0 = blockIdx.x * 64;
    {
        const int nfl4 = ((NN - row0) < 64 ? (NN - row0) : 64) * 16;
        const float4* __restrict__ xg = (const float4*)(x + (size_t)row0 * 64);
        float4* __restrict__ xl4 = (float4*)xl;
        for (int i = tid; i < nfl4; i += 256) xl4[i] = xg[i];
    }
    __syncthreads();
    const int wid = tid >> 6, lane = tid & 63;
    float wreg[64];
#pragma unroll
    for (int k = 0; k < 64; ++k) wreg[k] = Wl[k * 64 + lane];
    const int rbase = wid * 16;
#pragma unroll 1
    for (int r = 0; r < 16; ++r) {
        const int row = row0 + rbase + r;
        if (row >= NN) break;  // wave-uniform
        const float4* __restrict__ xr4 = (const float4*)(xl + (rbase + r) * 64);
        float sum = 0.0f;
#pragma unroll
        for (int q = 0; q < 16; ++q) {
            const float4 xv = xr4[q];  // ds_read_b128 broadcast
            sum = fmaf(xv.x, wreg[4 * q + 0], sum);
            sum = fmaf(xv.y, wreg[4 * q + 1], sum);
            sum = fmaf(xv.z, wreg[4 * q + 2], sum);
            sum = fmaf(xv.w, wreg[4 * q + 3], sum);
        }
        const float dv = rsqrtf(1.0f + (float)deg[row]);
        xsh[(size_t)row * 64 + lane] = __float2bfloat16(sum * dv);
    }
}

#define UNPK8(v, p0, p1, p2, p3, p4, p5, p6, p7)                      \
    p0 += __uint_as_float((v).x << 16); p1 += __uint_as_float((v).x & 0xffff0000u); \
    p2 += __uint_as_float((v).y << 16); p3 += __uint_as_float((v).y & 0xffff0000u); \
    p4 += __uint_as_float((v).z << 16); p5 += __uint_as_float((v).z & 0xffff0000u); \
    p6 += __uint_as_float((v).w << 16); p7 += __uint_as_float((v).w & 0xffff0000u);

// Fused per-HALF-bucket sort + aggregate + epilogue. 2 blocks/bucket, 32 nodes
// each. Gather uses oct-lanes: o=lane>>3 edge slot (8 edges/wave-load),
// sl=lane&7 dim-oct (uint4 = 8 bf16 dims). 2 predicated uint4 loads per
// 16-edge iter = ~32 lines in flight/wave. No shfl in predicated regions.
__global__ __launch_bounds__(256) void k_sagg(const unsigned* __restrict__ packed,
                                              const int* __restrict__ bstart,
                                              const __hip_bfloat16* __restrict__ xsh,
                                              const float* __restrict__ bias,
                                              float* __restrict__ out) {
    __shared__ unsigned sorted[HCAP];  // 6 KB
    __shared__ int hist[32];
    __shared__ int pref[32];
    __shared__ int cur[32];
    __shared__ float sdinv[32];
    const int tid = threadIdx.x;
    const int b = blockIdx.x >> 1;         // bucket
    const unsigned half = blockIdx.x & 1;  // 0: tl 0..31, 1: tl 32..63
    int s = bstart[b], e = bstart[b + 1];
    if (s < 0) s = 0;
    if (e > NE) e = NE;
    if (e < s) e = s;
    if (tid < 32) hist[tid] = 0;
    __syncthreads();
    for (int i = s + tid; i < e; i += 256) {
        const unsigned pk = packed[i];
        if (((pk >> 22) & 1u) == half) atomicAdd(&hist[(pk >> 17) & 31u], 1);
    }
    __syncthreads();
    if (tid == 0) {
        int run = 0;
        for (int t = 0; t < 32; ++t) { pref[t] = run; run += hist[t]; }
    }
    __syncthreads();
    const int hcnt = pref[31] + hist[31];
    const bool oversize = (hcnt > HCAP);
    if (tid < 32) {
        cur[tid] = pref[tid];
        sdinv[tid] = rsqrtf(1.0f + (float)hist[tid]);
    }
    __syncthreads();
    if (!oversize) {
        for (int i = s + tid; i < e; i += 256) {
            const unsigned pk = packed[i];
            if (((pk >> 22) & 1u) == half) {
                const int pos = atomicAdd(&cur[(pk >> 17) & 31u], 1);
                if (pos < HCAP) sorted[pos] = pk & 0x1FFFFu;
            }
        }
    }
    __syncthreads();

    const int wid = tid >> 6, lane = tid & 63;
    const int o = lane >> 3, sl = lane & 7;    // edge slot, dim-oct
    const uint4* __restrict__ xs8 = (const uint4*)xsh;  // 8 bf16 per elem
    const float bv = bias[lane];
#pragma unroll 1
    for (int t = 0; t < 8; ++t) {
        const int nl = wid * 8 + t;            // 0..31 within half
        const int c = b * 64 + (int)half * 32 + nl;
        if (c >= NN) break;  // wave-uniform
        const int off = pref[nl];
        int deg = hist[nl];
        deg = (deg < 0) ? 0 : (deg > hcnt ? hcnt : deg);  // defensive
        float ax0=0.f,ax1=0.f,ay0=0.f,ay1=0.f,az0=0.f,az1=0.f,aw0=0.f,aw1=0.f;
        float bx0=0.f,bx1=0.f,by0=0.f,by1=0.f,bz0=0.f,bz1=0.f,bw0=0.f,bw1=0.f;
        if (o == 0) {  // self-loop term (8 lanes cover the row)
            const uint4 v = xs8[(size_t)c * 8 + sl];
            UNPK8(v, ax0, ax1, ay0, ay1, az0, az1, aw0, aw1)
        }
        if (!oversize) {
            for (int j = 0; j < deg; j += 16) {  // 2 uint4 loads in flight
                const int e0 = j + o, e1 = j + 8 + o;
                uint4 v0 = {0u, 0u, 0u, 0u}, v1 = {0u, 0u, 0u, 0u};
                if (e0 < deg) v0 = xs8[(size_t)sorted[off + e0] * 8 + sl];
                if (e1 < deg) v1 = xs8[(size_t)sorted[off + e1] * 8 + sl];
                UNPK8(v0, ax0, ax1, ay0, ay1, az0, az1, aw0, aw1)
                UNPK8(v1, bx0, bx1, by0, by1, bz0, bz1, bw0, bw1)
            }
        } else {  // scan-mode fallback: unsorted global segment, tl-tagged
            if (o == 0) {
                const unsigned tl = (unsigned)((int)half * 32 + nl);
                for (int i = s; i < e; ++i) {
                    const unsigned pk = packed[i];
                    if ((pk >> 17) == tl) {
                        const uint4 v = xs8[(size_t)(pk & 0x1FFFFu) * 8 + sl];
                        UNPK8(v, ax0, ax1, ay0, ay1, az0, az1, aw0, aw1)
                    }
                }
            }
        }
        // merge chains (uniform from here on: all lanes active)
        ax0 += bx0; ax1 += bx1; ay0 += by0; ay1 += by1;
        az0 += bz0; az1 += bz1; aw0 += bw0; aw1 += bw1;
        // reduce across the 8 edge slots (lane bits 3,4,5)
#define RED3(a) a += __shfl_xor(a, 8); a += __shfl_xor(a, 16); a += __shfl_xor(a, 32);
        RED3(ax0) RED3(ax1) RED3(ay0) RED3(ay1)
        RED3(az0) RED3(az1) RED3(aw0) RED3(aw1)
#undef RED3
        // redistribute: lane l takes dim l = comp (l&7) from lane l>>3
        const float s0 = __shfl(ax0, lane >> 3);
        const float s1 = __shfl(ax1, lane >> 3);
        const float s2 = __shfl(ay0, lane >> 3);
        const float s3 = __shfl(ay1, lane >> 3);
        const float s4 = __shfl(az0, lane >> 3);
        const float s5 = __shfl(az1, lane >> 3);
        const float s6 = __shfl(aw0, lane >> 3);
        const float s7 = __shfl(aw1, lane >> 3);
        const float r01 = (lane & 1) ? s1 : s0;
        const float r23 = (lane & 1) ? s3 : s2;
        const float r45 = (lane & 1) ? s5 : s4;
        const float r67 = (lane & 1) ? s7 : s6;
        const float r03 = (lane & 2) ? r23 : r01;
        const float r47 = (lane & 2) ? r67 : r45;
        const float a = (lane & 4) ? r47 : r03;
        const int p = c * 64 + lane;
        unsigned o0, o1;
        threefry2x32(0u, 42u, 0u, (unsigned)p, o0, o1);
        const unsigned bits = o0 ^ o1;
        const float u = __uint_as_float((bits >> 9) | 0x3f800000u) - 1.0f;
        const float h = tanhf(sdinv[nl] * a + bv);
        out[p] = (u < 0.9f) ? h / 0.9f : 0.0f;
    }
}

extern "C" void kernel_launch(void* const* d_in, const int* in_sizes, int n_in,
                              void* d_out, int out_size, void* d_ws, size_t ws_size,
                              hipStream_t stream) {
    const float* x  = (const float*)d_in[0];
    const float* W  = (const float*)d_in[1];
    const float* b  = (const float*)d_in[2];
    const int*   ei = (const int*)d_in[3];
    float* out = (float*)d_out;

    int* deg = (int*)d_ws;                                  // i32[NN]
    int* bhist = deg + NN;                                  // i32[NBUCK]
    __hip_bfloat16* xsh = (__hip_bfloat16*)(bhist + NBUCK); // bf16[NN*64]
    unsigned* packed = (unsigned*)(xsh + (size_t)NN * 64);  // u32[NE]
    int* bstart = (int*)(packed + NE);                      // i32[NBUCK+1]
    int* bcur   = bstart + NBUCK + 1;                       // i32[NBUCK]

    hipMemsetAsync(deg, 0, (NN + NBUCK) * sizeof(int), stream);  // deg + bhist
    k_bhist<<<P1B, P1T, 0, stream>>>(ei, bhist, deg);
    k_bscan<<<1, 1024, 0, stream>>>(bhist, bstart, bcur);
    k_p1<<<P1B, P1T, 0, stream>>>(ei, bcur, packed);
    k_xw<<<(NN + 63) / 64, 256, 0, stream>>>(x, W, deg, xsh);
    k_sagg<<<NBUCK * 2, 256, 0, stream>>>(packed, bstart, xsh, b, out);
}

// Round 17
// 154.072 us; speedup vs baseline: 1.2273x; 1.2273x over previous
//
#include <hip/hip_runtime.h>
#include <hip/hip_bf16.h>

// GCNConv: fine bin (16 tgts/bucket) -> fused per-bucket {LDS counting sort +
// per-node quarter-lane gather + epilogue}. No fp32 global atomics.
// agg[c] = dinv[c] * ( xs[c] + sum_{e: col[e]==c} xs[row[e]] ),
//   xs[i] = (x@W)[i] * dinv[i],  dinv[i] = rsqrt(1 + indeg(i))
// out = dropout(tanh(agg + b)), JAX partitionable-threefry key (0,42), p_keep=0.9:
//   bits[p] = o0^o1 of threefry((0,42), 0, p); u = bitcast(bits>>9|0x3f800000)-1; keep = u<0.9.
//
// R8: __shfl only in uniform regions (predicated regions contain loads only).
// R15: quarter-lane uint2 gather, 61us @61% occ — FETCH 85MB = compulsory floor.
// R16 lessons (reverted): per-node global deg atomics = 50MB writes; uint4
//   oct-lanes doubled FETCH (L2 reuse window halved). R17: same gather shape,
//   16-tgt fine buckets -> 6250 sagg blocks (24/CU) for occupancy, no re-scan.
//
// ws (~19.7 MB): dinv f32[NN] | xsh bf16[NN*64] | packed u32[NE] |
//                bhist i32[NB2] | bstart i32[NB2+1] | bcur i32[NB2]

#define NN 100000
#define NE 1600000
#define NB2 6250            // NN/16 exactly; bucket = tgt>>4
#define P1B 128
#define P1T 1024
#define CHUNK 12500         // P1B * CHUNK == NE
#define HCAP 768            // per-bucket LDS sort capacity (mean 256, +32 sigma)

// ---------------- Threefry2x32 (JAX-exact) ----------------
__device__ __forceinline__ unsigned rotl32(unsigned x, int r) {
    return (x << r) | (x >> (32 - r));
}

__device__ __forceinline__ void threefry2x32(unsigned k0, unsigned k1,
                                             unsigned x0, unsigned x1,
                                             unsigned& o0, unsigned& o1) {
    const unsigned ks0 = k0, ks1 = k1, ks2 = k0 ^ k1 ^ 0x1BD11BDAu;
    x0 += ks0; x1 += ks1;
    x0 += x1; x1 = rotl32(x1, 13); x1 ^= x0;
    x0 += x1; x1 = rotl32(x1, 15); x1 ^= x0;
    x0 += x1; x1 = rotl32(x1, 26); x1 ^= x0;
    x0 += x1; x1 = rotl32(x1, 6);  x1 ^= x0;
    x0 += ks1; x1 += ks2 + 1u;
    x0 += x1; x1 = rotl32(x1, 17); x1 ^= x0;
    x0 += x1; x1 = rotl32(x1, 29); x1 ^= x0;
    x0 += x1; x1 = rotl32(x1, 16); x1 ^= x0;
    x0 += x1; x1 = rotl32(x1, 24); x1 ^= x0;
    x0 += ks2; x1 += ks0 + 2u;
    x0 += x1; x1 = rotl32(x1, 13); x1 ^= x0;
    x0 += x1; x1 = rotl32(x1, 15); x1 ^= x0;
    x0 += x1; x1 = rotl32(x1, 26); x1 ^= x0;
    x0 += x1; x1 = rotl32(x1, 6);  x1 ^= x0;
    x0 += ks0; x1 += ks1 + 3u;
    x0 += x1; x1 = rotl32(x1, 17); x1 ^= x0;
    x0 += x1; x1 = rotl32(x1, 29); x1 ^= x0;
    x0 += x1; x1 = rotl32(x1, 16); x1 ^= x0;
    x0 += x1; x1 = rotl32(x1, 24); x1 ^= x0;
    x0 += ks1; x1 += ks2 + 4u;
    x0 += x1; x1 = rotl32(x1, 13); x1 ^= x0;
    x0 += x1; x1 = rotl32(x1, 15); x1 ^= x0;
    x0 += x1; x1 = rotl32(x1, 26); x1 ^= x0;
    x0 += x1; x1 = rotl32(x1, 6);  x1 ^= x0;
    x0 += ks2; x1 += ks0 + 5u;
    o0 = x0; o1 = x1;
}

// ---------------- Kernels ----------------
__global__ __launch_bounds__(P1T) void k_bhist(const int* __restrict__ ei,
                                               int* __restrict__ bhist) {
    __shared__ int h[NB2];  // 25 KB
    const int tid = threadIdx.x;
    for (int i = tid; i < NB2; i += P1T) h[i] = 0;
    __syncthreads();
    const int base = blockIdx.x * CHUNK;
    for (int i = tid; i < CHUNK; i += P1T) {
        const unsigned t = (unsigned)ei[NE + base + i];
        if (t < NN) atomicAdd(&h[t >> 4], 1);
    }
    __syncthreads();
    for (int i = tid; i < NB2; i += P1T) {
        const int v = h[i];
        if (v) atomicAdd(&bhist[i], v);
    }
}

// Exclusive scan of bhist[NB2] in one block: 7 elems/thread + LDS scan.
__global__ __launch_bounds__(1024) void k_bscan(const int* __restrict__ bhist,
                                                int* __restrict__ bstart,
                                                int* __restrict__ bcur) {
    __shared__ int partial[1024];
    const int t = threadIdx.x;
    const int base = t * 7;
    int vals[7];
    int run = 0;
#pragma unroll
    for (int k = 0; k < 7; ++k) {
        const int idx = base + k;
        const int v = (idx < NB2) ? bhist[idx] : 0;
        vals[k] = run;   // exclusive within thread
        run += v;
    }
    partial[t] = run;
    __syncthreads();
    for (int d = 1; d < 1024; d <<= 1) {
        const int v = (t >= d) ? partial[t - d] : 0;
        __syncthreads();
        partial[t] += v;
        __syncthreads();
    }
    const int ex = partial[t] - run;  // exclusive offset of this thread's range
#pragma unroll
    for (int k = 0; k < 7; ++k) {
        const int idx = base + k;
        if (idx < NB2) {
            const int bs = ex + vals[k];
            bstart[idx] = bs;
            bcur[idx] = bs;
        }
    }
    if (t == 0) bstart[NB2] = NE;
}

__global__ __launch_bounds__(P1T) void k_p1(const int* __restrict__ ei,
                                            int* __restrict__ bcur,
                                            unsigned* __restrict__ packed) {
    __shared__ int hb[NB2];  // 25 KB
    __shared__ int lc[NB2];  // 25 KB
    const int tid = threadIdx.x;
    for (int i = tid; i < NB2; i += P1T) { hb[i] = 0; lc[i] = 0; }
    __syncthreads();
    const int base = blockIdx.x * CHUNK;
    for (int i = tid; i < CHUNK; i += P1T) {
        const unsigned t = (unsigned)ei[NE + base + i];
        if (t < NN) atomicAdd(&hb[t >> 4], 1);
    }
    __syncthreads();
    for (int i = tid; i < NB2; i += P1T) {
        const int h = hb[i];
        hb[i] = h ? atomicAdd(&bcur[i], h) : 0;
    }
    __syncthreads();
    for (int i = tid; i < CHUNK; i += P1T) {
        const unsigned t = (unsigned)ei[NE + base + i];
        if (t >= NN) continue;
        const unsigned src = (unsigned)ei[base + i];
        const int bk = t >> 4;
        const unsigned pos = (unsigned)(hb[bk] + atomicAdd(&lc[bk], 1));
        if (pos < NE) packed[pos] = src | ((t & 63u) << 17);
    }
}

// Per-bucket degree hist -> dinv (needed by k_xw before k_sagg).
__global__ __launch_bounds__(256) void k_deg(const unsigned* __restrict__ packed,
                                             const int* __restrict__ bstart,
                                             float* __restrict__ dinv) {
    __shared__ int hist[16];
    const int tid = threadIdx.x;
    const int b = blockIdx.x;
    int s = bstart[b], e = bstart[b + 1];
    if (s < 0) s = 0;
    if (e > NE) e = NE;
    if (tid < 16) hist[tid] = 0;
    __syncthreads();
    for (int i = s + tid; i < e; i += 256) atomicAdd(&hist[(packed[i] >> 17) & 15u], 1);
    __syncthreads();
    if (tid < 16) {
        const int c = b * 16 + tid;
        if (c < NN) dinv[c] = rsqrtf(1.0f + (float)hist[tid]);
    }
}

// x@W: W register-resident, x rows staged in LDS, distributed per-row via
// ds_read_b128 broadcasts + 64 register FMAs. 64 rows/block, 16/wave.
__global__ __launch_bounds__(256) void k_xw(const float* __restrict__ x,
                                            const float* __restrict__ W,
                                            const float* __restrict__ dinv,
                                            __hip_bfloat16* __restrict__ xsh) {
    __shared__ float Wl[64 * 64];   // 16 KB
    __shared__ float xl[64 * 64];   // 16 KB
    const int tid = threadIdx.x;
    for (int i = tid; i < 64 * 64; i += 256) Wl[i] = W[i];  // coalesced
    const int row0 = blockIdx.x * 64;
    {
        const int nfl4 = ((NN - row0) < 64 ? (NN - row0) : 64) * 16;
        const float4* __restrict__ xg = (const float4*)(x + (size_t)row0 * 64);
        float4* __restrict__ xl4 = (float4*)xl;
        for (int i = tid; i < nfl4; i += 256) xl4[i] = xg[i];
    }
    __syncthreads();
    const int wid = tid >> 6, lane = tid & 63;
    float wreg[64];
#pragma unroll
    for (int k = 0; k < 64; ++k) wreg[k] = Wl[k * 64 + lane];
    const int rbase = wid * 16;
#pragma unroll 1
    for (int r = 0; r < 16; ++r) {
        const int row = row0 + rbase + r;
        if (row >= NN) break;  // wave-uniform
        const float4* __restrict__ xr4 = (const float4*)(xl + (rbase + r) * 64);
        float sum = 0.0f;
#pragma unroll
        for (int q = 0; q < 16; ++q) {
            const float4 xv = xr4[q];  // ds_read_b128 broadcast
            sum = fmaf(xv.x, wreg[4 * q + 0], sum);
            sum = fmaf(xv.y, wreg[4 * q + 1], sum);
            sum = fmaf(xv.z, wreg[4 * q + 2], sum);
            sum = fmaf(xv.w, wreg[4 * q + 3], sum);
        }
        xsh[(size_t)row * 64 + lane] = __float2bfloat16(sum * dinv[row]);
    }
}

// Fused per-bucket sort + aggregate + epilogue. One block per 16-node bucket
// (6250 blocks, ~24/CU): hist -> prefix+dinv -> LDS counting sort -> per-node
// gather with R15's quarter-lanes (q=lane>>4 edge slot, sl=lane&15 = dims
// 4sl..4sl+3 as uint2). No shfl in predicated code; uniform combines.
__global__ __launch_bounds__(256) void k_sagg(const unsigned* __restrict__ packed,
                                              const int* __restrict__ bstart,
                                              const __hip_bfloat16* __restrict__ xsh,
                                              const float* __restrict__ bias,
                                              float* __restrict__ out) {
    __shared__ unsigned sorted[HCAP];  // 3 KB
    __shared__ int hist[16];
    __shared__ int pref[16];
    __shared__ int cur[16];
    __shared__ float sdinv[16];
    const int tid = threadIdx.x;
    const int b = blockIdx.x;
    int s = bstart[b], e = bstart[b + 1];
    if (s < 0) s = 0;
    if (e > NE) e = NE;
    if (e < s) e = s;
    const int seg = e - s;
    const bool oversize = (seg > HCAP);
    if (tid < 16) hist[tid] = 0;
    __syncthreads();
    for (int i = s + tid; i < e; i += 256) atomicAdd(&hist[(packed[i] >> 17) & 15u], 1);
    __syncthreads();
    if (tid == 0) {
        int run = 0;
        for (int t = 0; t < 16; ++t) { pref[t] = run; run += hist[t]; }
    }
    __syncthreads();
    if (tid < 16) {
        cur[tid] = pref[tid];
        sdinv[tid] = rsqrtf(1.0f + (float)hist[tid]);
    }
    __syncthreads();
    if (!oversize) {
        for (int i = s + tid; i < e; i += 256) {
            const unsigned pk = packed[i];
            const int pos = atomicAdd(&cur[(pk >> 17) & 15u], 1);
            if (pos < HCAP) sorted[pos] = pk & 0x1FFFFu;
        }
    }
    __syncthreads();

    const int wid = tid >> 6, lane = tid & 63;
    const int q = lane >> 4, sl = lane & 15;   // quarter, dim-quad
    const uint2* __restrict__ xs4 = (const uint2*)xsh;  // 4 bf16 per elem
    const float bv = bias[lane];
#pragma unroll 1
    for (int t = 0; t < 4; ++t) {
        const int nl = wid * 4 + t;            // 0..15 within bucket
        const int c = b * 16 + nl;             // NB2*16 == NN exactly
        if (c >= NN) break;  // wave-uniform (defensive)
        const int off = pref[nl];
        int deg = hist[nl];
        deg = (deg < 0) ? 0 : (deg > seg ? seg : deg);  // defensive
        float4 a0 = {0.f, 0.f, 0.f, 0.f}, a1 = {0.f, 0.f, 0.f, 0.f};
        if (q == 0) {  // self-loop term (counted once)
            const uint2 v = xs4[(size_t)c * 16 + sl];
            a0.x += __uint_as_float(v.x << 16);
            a0.y += __uint_as_float(v.x & 0xffff0000u);
            a0.z += __uint_as_float(v.y << 16);
            a0.w += __uint_as_float(v.y & 0xffff0000u);
        }
        if (!oversize) {
            int j = 0;
            for (; j + 7 < deg; j += 8) {  // 8 edges: 2 chains x 4 quarters
                const int s0 = (int)sorted[off + j + q];
                const int s1 = (int)sorted[off + j + 4 + q];
                const uint2 v0 = xs4[(size_t)s0 * 16 + sl];
                const uint2 v1 = xs4[(size_t)s1 * 16 + sl];
                a0.x += __uint_as_float(v0.x << 16); a0.y += __uint_as_float(v0.x & 0xffff0000u);
                a0.z += __uint_as_float(v0.y << 16); a0.w += __uint_as_float(v0.y & 0xffff0000u);
                a1.x += __uint_as_float(v1.x << 16); a1.y += __uint_as_float(v1.x & 0xffff0000u);
                a1.z += __uint_as_float(v1.y << 16); a1.w += __uint_as_float(v1.y & 0xffff0000u);
            }
            for (; j < deg; j += 4) {  // tail: predicated loads, no shfl
                const int eo = j + q;
                if (eo < deg) {
                    const int s0 = (int)sorted[off + eo];
                    const uint2 v = xs4[(size_t)s0 * 16 + sl];
                    a0.x += __uint_as_float(v.x << 16);
                    a0.y += __uint_as_float(v.x & 0xffff0000u);
                    a0.z += __uint_as_float(v.y << 16);
                    a0.w += __uint_as_float(v.y & 0xffff0000u);
                }
            }
        } else {  // scan-mode fallback: unsorted global segment, tl-tagged
            if (q == 0) {
                const unsigned tl = (unsigned)nl;
                for (int i = s; i < e; ++i) {
                    const unsigned pk = packed[i];
                    if (((pk >> 17) & 15u) == tl) {
                        const uint2 v = xs4[(size_t)(pk & 0x1FFFFu) * 16 + sl];
                        a0.x += __uint_as_float(v.x << 16);
                        a0.y += __uint_as_float(v.x & 0xffff0000u);
                        a0.z += __uint_as_float(v.y << 16);
                        a0.w += __uint_as_float(v.y & 0xffff0000u);
                    }
                }
            }
        }
        // combine chains, then quarters (uniform shfls, all lanes active)
        float ax = a0.x + a1.x, ay = a0.y + a1.y;
        float az = a0.z + a1.z, aw = a0.w + a1.w;
        ax += __shfl_xor(ax, 16); ax += __shfl_xor(ax, 32);
        ay += __shfl_xor(ay, 16); ay += __shfl_xor(ay, 32);
        az += __shfl_xor(az, 16); az += __shfl_xor(az, 32);
        aw += __shfl_xor(aw, 16); aw += __shfl_xor(aw, 32);
        // redistribute: lane l takes dim l = comp (l&3) from lane l>>2
        const float sx = __shfl(ax, lane >> 2);
        const float sy = __shfl(ay, lane >> 2);
        const float sz = __shfl(az, lane >> 2);
        const float sw = __shfl(aw, lane >> 2);
        const float ab = (lane & 1) ? sy : sx;
        const float cd = (lane & 1) ? sw : sz;
        const float a = (lane & 2) ? cd : ab;
        const int p = c * 64 + lane;
        unsigned o0, o1;
        threefry2x32(0u, 42u, 0u, (unsigned)p, o0, o1);
        const unsigned bits = o0 ^ o1;
        const float u = __uint_as_float((bits >> 9) | 0x3f800000u) - 1.0f;
        const float h = tanhf(sdinv[nl] * a + bv);
        out[p] = (u < 0.9f) ? h / 0.9f : 0.0f;
    }
}

extern "C" void kernel_launch(void* const* d_in, const int* in_sizes, int n_in,
                              void* d_out, int out_size, void* d_ws, size_t ws_size,
                              hipStream_t stream) {
    const float* x  = (const float*)d_in[0];
    const float* W  = (const float*)d_in[1];
    const float* b  = (const float*)d_in[2];
    const int*   ei = (const int*)d_in[3];
    float* out = (float*)d_out;

    float* dinv = (float*)d_ws;                             // f32[NN]
    __hip_bfloat16* xsh = (__hip_bfloat16*)(dinv + NN);     // bf16[NN*64]
    unsigned* packed = (unsigned*)(xsh + (size_t)NN * 64);  // u32[NE]
    int* bhist  = (int*)(packed + NE);                      // i32[NB2]
    int* bstart = bhist + NB2;                              // i32[NB2+1]
    int* bcur   = bstart + NB2 + 1;                         // i32[NB2]

    hipMemsetAsync(bhist, 0, NB2 * sizeof(int), stream);
    k_bhist<<<P1B, P1T, 0, stream>>>(ei, bhist);
    k_bscan<<<1, 1024, 0, stream>>>(bhist, bstart, bcur);
    k_p1<<<P1B, P1T, 0, stream>>>(ei, bcur, packed);
    k_deg<<<NB2, 256, 0, stream>>>(packed, bstart, dinv);
    k_xw<<<(NN + 63) / 64, 256, 0, stream>>>(x, W, dinv, xsh);
    k_sagg<<<NB2, 256, 0, stream>>>(packed, bstart, xsh, b, out);
}

// Round 18
// 144.737 us; speedup vs baseline: 1.3064x; 1.0645x over previous
//
#include <hip/hip_runtime.h>
#include <hip/hip_bf16.h>

// GCNConv: coarse bin (64 tgts/bucket) -> fused per-half-bucket {LDS counting
// sort + per-node quarter-lane gather + epilogue}. No fp32 global atomics.
// agg[c] = dinv[c] * ( xs[c] + sum_{e: col[e]==c} xs[row[e]] ),
//   xs[i] = (x@W)[i] * dinv[i],  dinv[i] = rsqrt(1 + indeg(i))
// out = dropout(tanh(agg + b)), JAX partitionable-threefry key (0,42), p_keep=0.9:
//   bits[p] = o0^o1 of threefry((0,42), 0, p); u = bitcast(bits>>9|0x3f800000)-1; keep = u<0.9.
//
// R8: __shfl only in uniform regions (predicated regions contain loads only).
// R15: quarter-lane uint2 gather @61us, 64-bucket plumbing cheapest so far.
// R16/R17 lessons: global deg atomics = 50MB writes; uint4 halves L2 reuse;
//   fine buckets trade 3us sagg for 11us plumbing. R18: R15 structure, minus
//   redundant passes — bh_part persists bhist's per-block hists (p1 skips its
//   hist pass); k_deg fused into k_xw (block b == bucket b hists its segment).
//
// ws (~20.0 MB): xsh bf16[NN*64] | packed u32[NE] | bhist i32[NBUCK] |
//                bstart i32[NBUCK+1] | bcur i32[NBUCK] | bh_part i32[P1B*NBUCK]

#define NN 100000
#define NE 1600000
#define NBUCK 1563
#define P1B 128
#define P1T 1024
#define CHUNK 12500         // P1B * CHUNK == NE
#define HCAP 1536           // per-half-bucket LDS sort capacity (mean 512)

// ---------------- Threefry2x32 (JAX-exact) ----------------
__device__ __forceinline__ unsigned rotl32(unsigned x, int r) {
    return (x << r) | (x >> (32 - r));
}

__device__ __forceinline__ void threefry2x32(unsigned k0, unsigned k1,
                                             unsigned x0, unsigned x1,
                                             unsigned& o0, unsigned& o1) {
    const unsigned ks0 = k0, ks1 = k1, ks2 = k0 ^ k1 ^ 0x1BD11BDAu;
    x0 += ks0; x1 += ks1;
    x0 += x1; x1 = rotl32(x1, 13); x1 ^= x0;
    x0 += x1; x1 = rotl32(x1, 15); x1 ^= x0;
    x0 += x1; x1 = rotl32(x1, 26); x1 ^= x0;
    x0 += x1; x1 = rotl32(x1, 6);  x1 ^= x0;
    x0 += ks1; x1 += ks2 + 1u;
    x0 += x1; x1 = rotl32(x1, 17); x1 ^= x0;
    x0 += x1; x1 = rotl32(x1, 29); x1 ^= x0;
    x0 += x1; x1 = rotl32(x1, 16); x1 ^= x0;
    x0 += x1; x1 = rotl32(x1, 24); x1 ^= x0;
    x0 += ks2; x1 += ks0 + 2u;
    x0 += x1; x1 = rotl32(x1, 13); x1 ^= x0;
    x0 += x1; x1 = rotl32(x1, 15); x1 ^= x0;
    x0 += x1; x1 = rotl32(x1, 26); x1 ^= x0;
    x0 += x1; x1 = rotl32(x1, 6);  x1 ^= x0;
    x0 += ks0; x1 += ks1 + 3u;
    x0 += x1; x1 = rotl32(x1, 17); x1 ^= x0;
    x0 += x1; x1 = rotl32(x1, 29); x1 ^= x0;
    x0 += x1; x1 = rotl32(x1, 16); x1 ^= x0;
    x0 += x1; x1 = rotl32(x1, 24); x1 ^= x0;
    x0 += ks1; x1 += ks2 + 4u;
    x0 += x1; x1 = rotl32(x1, 13); x1 ^= x0;
    x0 += x1; x1 = rotl32(x1, 15); x1 ^= x0;
    x0 += x1; x1 = rotl32(x1, 26); x1 ^= x0;
    x0 += x1; x1 = rotl32(x1, 6);  x1 ^= x0;
    x0 += ks2; x1 += ks0 + 5u;
    o0 = x0; o1 = x1;
}

// ---------------- Kernels ----------------
// Bucket histogram; per-block hists persisted to bh_part for k_p1 reuse.
__global__ __launch_bounds__(P1T) void k_bhist(const int* __restrict__ ei,
                                               int* __restrict__ bhist,
                                               int* __restrict__ bh_part) {
    __shared__ int h[NBUCK];
    const int tid = threadIdx.x;
    for (int i = tid; i < NBUCK; i += P1T) h[i] = 0;
    __syncthreads();
    const int base = blockIdx.x * CHUNK;
    for (int i = tid; i < CHUNK; i += P1T) {
        const unsigned t = (unsigned)ei[NE + base + i];
        if (t < NN) atomicAdd(&h[t >> 6], 1);
    }
    __syncthreads();
    int* __restrict__ part = bh_part + (size_t)blockIdx.x * NBUCK;
    for (int i = tid; i < NBUCK; i += P1T) {
        const int v = h[i];
        part[i] = v;                      // persist for k_p1
        if (v) atomicAdd(&bhist[i], v);
    }
}

__global__ __launch_bounds__(1024) void k_bscan(const int* __restrict__ bhist,
                                                int* __restrict__ bstart,
                                                int* __restrict__ bcur) {
    __shared__ int s[2048];
    const int t = threadIdx.x;
    const int i0 = t, i1 = t + 1024;
    const int c0 = (i0 < NBUCK) ? bhist[i0] : 0;
    const int c1 = (i1 < NBUCK) ? bhist[i1] : 0;
    s[i0] = c0; s[i1] = c1;
    __syncthreads();
    for (int d = 1; d < 2048; d <<= 1) {
        const int a0 = (i0 >= d) ? s[i0 - d] : 0;
        const int a1 = (i1 >= d) ? s[i1 - d] : 0;
        __syncthreads();
        s[i0] += a0; s[i1] += a1;
        __syncthreads();
    }
    if (i0 < NBUCK) { const int b = s[i0] - c0; bstart[i0] = b; bcur[i0] = b; }
    if (i1 < NBUCK) { const int b = s[i1] - c1; bstart[i1] = b; bcur[i1] = b; }
    if (t == 0) bstart[NBUCK] = NE;
}

// Bin edges. Hist pass REPLACED by reloading bh_part (saves a 12.8MB ei pass).
__global__ __launch_bounds__(P1T) void k_p1(const int* __restrict__ ei,
                                            const int* __restrict__ bh_part,
                                            int* __restrict__ bcur,
                                            unsigned* __restrict__ packed) {
    __shared__ int hb[NBUCK];
    __shared__ int lc[NBUCK];
    const int tid = threadIdx.x;
    const int* __restrict__ part = bh_part + (size_t)blockIdx.x * NBUCK;
    for (int i = tid; i < NBUCK; i += P1T) {
        const int h = part[i];            // this block's hist (from k_bhist)
        hb[i] = h ? atomicAdd(&bcur[i], h) : 0;
        lc[i] = 0;
    }
    __syncthreads();
    const int base = blockIdx.x * CHUNK;
    for (int i = tid; i < CHUNK; i += P1T) {
        const unsigned t = (unsigned)ei[NE + base + i];
        if (t >= NN) continue;
        const unsigned src = (unsigned)ei[base + i];
        const int bk = t >> 6;
        const unsigned pos = (unsigned)(hb[bk] + atomicAdd(&lc[bk], 1));
        if (pos < NE) packed[pos] = src | ((t & 63u) << 17);
    }
}

// x@W with k_deg FUSED: block b == bucket b; hist its packed segment -> dinv
// in LDS (no global dinv array). W register-resident; x rows staged in LDS,
// distributed per-row via ds_read_b128 broadcasts + 64 register FMAs.
__global__ __launch_bounds__(256) void k_xw(const float* __restrict__ x,
                                            const float* __restrict__ W,
                                            const unsigned* __restrict__ packed,
                                            const int* __restrict__ bstart,
                                            __hip_bfloat16* __restrict__ xsh) {
    __shared__ float Wl[64 * 64];   // 16 KB
    __shared__ float xl[64 * 64];   // 16 KB
    __shared__ int hist[64];
    __shared__ float sdinv[64];
    const int tid = threadIdx.x;
    const int b = blockIdx.x;       // grid == NBUCK
    const int row0 = b * 64;
    for (int i = tid; i < 64 * 64; i += 256) Wl[i] = W[i];  // coalesced
    {
        const int nrow = (NN - row0) < 64 ? (NN - row0) : 64;
        const int nfl4 = nrow * 16;
        const float4* __restrict__ xg = (const float4*)(x + (size_t)row0 * 64);
        float4* __restrict__ xl4 = (float4*)xl;
        for (int i = tid; i < nfl4; i += 256) xl4[i] = xg[i];
    }
    if (tid < 64) hist[tid] = 0;
    __syncthreads();
    {   // degree hist of this bucket's segment (coalesced, ~1024 edges)
        int s = bstart[b], e = bstart[b + 1];
        if (s < 0) s = 0;
        if (e > NE) e = NE;
        for (int i = s + tid; i < e; i += 256) atomicAdd(&hist[packed[i] >> 17], 1);
    }
    __syncthreads();
    if (tid < 64) sdinv[tid] = rsqrtf(1.0f + (float)hist[tid]);
    __syncthreads();
    const int wid = tid >> 6, lane = tid & 63;
    float wreg[64];
#pragma unroll
    for (int k = 0; k < 64; ++k) wreg[k] = Wl[k * 64 + lane];
    const int rbase = wid * 16;
#pragma unroll 1
    for (int r = 0; r < 16; ++r) {
        const int row = row0 + rbase + r;
        if (row >= NN) break;  // wave-uniform
        const float4* __restrict__ xr4 = (const float4*)(xl + (rbase + r) * 64);
        float sum = 0.0f;
#pragma unroll
        for (int q = 0; q < 16; ++q) {
            const float4 xv = xr4[q];  // ds_read_b128 broadcast
            sum = fmaf(xv.x, wreg[4 * q + 0], sum);
            sum = fmaf(xv.y, wreg[4 * q + 1], sum);
            sum = fmaf(xv.z, wreg[4 * q + 2], sum);
            sum = fmaf(xv.w, wreg[4 * q + 3], sum);
        }
        xsh[(size_t)row * 64 + lane] = __float2bfloat16(sum * sdinv[rbase + r]);
    }
}

// Fused per-HALF-bucket sort + aggregate + epilogue (R15-proven). 2 blocks per
// bucket, 32 nodes each: hist(half) -> prefix+dinv -> LDS counting sort ->
// per-node gather with quarter-lanes (q=lane>>4 edge slot, sl=lane&15 holds
// dims 4sl..4sl+3 as one uint2). No shfl in predicated code; uniform combines.
__global__ __launch_bounds__(256) void k_sagg(const unsigned* __restrict__ packed,
                                              const int* __restrict__ bstart,
                                              const __hip_bfloat16* __restrict__ xsh,
                                              const float* __restrict__ bias,
                                              float* __restrict__ out) {
    __shared__ unsigned sorted[HCAP];  // 6 KB
    __shared__ int hist[32];
    __shared__ int pref[32];
    __shared__ int cur[32];
    __shared__ float sdinv[32];
    const int tid = threadIdx.x;
    const int b = blockIdx.x >> 1;         // bucket
    const unsigned half = blockIdx.x & 1;  // 0: tl 0..31, 1: tl 32..63
    int s = bstart[b], e = bstart[b + 1];
    if (s < 0) s = 0;
    if (e > NE) e = NE;
    if (e < s) e = s;
    if (tid < 32) hist[tid] = 0;
    __syncthreads();
    for (int i = s + tid; i < e; i += 256) {
        const unsigned pk = packed[i];
        if (((pk >> 22) & 1u) == half) atomicAdd(&hist[(pk >> 17) & 31u], 1);
    }
    __syncthreads();
    if (tid == 0) {
        int run = 0;
        for (int t = 0; t < 32; ++t) { pref[t] = run; run += hist[t]; }
    }
    __syncthreads();
    const int hcnt = pref[31] + hist[31];
    const bool oversize = (hcnt > HCAP);
    if (tid < 32) {
        cur[tid] = pref[tid];
        sdinv[tid] = rsqrtf(1.0f + (float)hist[tid]);
    }
    __syncthreads();
    if (!oversize) {
        for (int i = s + tid; i < e; i += 256) {
            const unsigned pk = packed[i];
            if (((pk >> 22) & 1u) == half) {
                const int pos = atomicAdd(&cur[(pk >> 17) & 31u], 1);
                if (pos < HCAP) sorted[pos] = pk & 0x1FFFFu;
            }
        }
    }
    __syncthreads();

    const int wid = tid >> 6, lane = tid & 63;
    const int q = lane >> 4, sl = lane & 15;   // quarter, dim-quad
    const uint2* __restrict__ xs4 = (const uint2*)xsh;  // 4 bf16 per elem
    const float bv = bias[lane];
#pragma unroll 1
    for (int t = 0; t < 8; ++t) {
        const int nl = wid * 8 + t;            // 0..31 within half
        const int c = b * 64 + (int)half * 32 + nl;
        if (c >= NN) break;  // wave-uniform
        const int off = pref[nl];
        int deg = hist[nl];
        deg = (deg < 0) ? 0 : (deg > hcnt ? hcnt : deg);  // defensive
        float4 a0 = {0.f, 0.f, 0.f, 0.f}, a1 = {0.f, 0.f, 0.f, 0.f};
        if (q == 0) {  // self-loop term (counted once)
            const uint2 v = xs4[(size_t)c * 16 + sl];
            a0.x += __uint_as_float(v.x << 16);
            a0.y += __uint_as_float(v.x & 0xffff0000u);
            a0.z += __uint_as_float(v.y << 16);
            a0.w += __uint_as_float(v.y & 0xffff0000u);
        }
        if (!oversize) {
            int j = 0;
            for (; j + 7 < deg; j += 8) {  // 8 edges: 2 chains x 4 quarters
                const int s0 = (int)sorted[off + j + q];
                const int s1 = (int)sorted[off + j + 4 + q];
                const uint2 v0 = xs4[(size_t)s0 * 16 + sl];
                const uint2 v1 = xs4[(size_t)s1 * 16 + sl];
                a0.x += __uint_as_float(v0.x << 16); a0.y += __uint_as_float(v0.x & 0xffff0000u);
                a0.z += __uint_as_float(v0.y << 16); a0.w += __uint_as_float(v0.y & 0xffff0000u);
                a1.x += __uint_as_float(v1.x << 16); a1.y += __uint_as_float(v1.x & 0xffff0000u);
                a1.z += __uint_as_float(v1.y << 16); a1.w += __uint_as_float(v1.y & 0xffff0000u);
            }
            for (; j < deg; j += 4) {  // tail: predicated loads, no shfl
                const int eo = j + q;
                if (eo < deg) {
                    const int s0 = (int)sorted[off + eo];
                    const uint2 v = xs4[(size_t)s0 * 16 + sl];
                    a0.x += __uint_as_float(v.x << 16);
                    a0.y += __uint_as_float(v.x & 0xffff0000u);
                    a0.z += __uint_as_float(v.y << 16);
                    a0.w += __uint_as_float(v.y & 0xffff0000u);
                }
            }
        } else {  // scan-mode fallback: unsorted global segment, tl-tagged
            if (q == 0) {
                const unsigned tl = (unsigned)((int)half * 32 + nl);
                for (int i = s; i < e; ++i) {
                    const unsigned pk = packed[i];
                    if ((pk >> 17) == tl) {
                        const uint2 v = xs4[(size_t)(pk & 0x1FFFFu) * 16 + sl];
                        a0.x += __uint_as_float(v.x << 16);
                        a0.y += __uint_as_float(v.x & 0xffff0000u);
                        a0.z += __uint_as_float(v.y << 16);
                        a0.w += __uint_as_float(v.y & 0xffff0000u);
                    }
                }
            }
        }
        // combine chains, then quarters (uniform shfls, all lanes active)
        float ax = a0.x + a1.x, ay = a0.y + a1.y;
        float az = a0.z + a1.z, aw = a0.w + a1.w;
        ax += __shfl_xor(ax, 16); ax += __shfl_xor(ax, 32);
        ay += __shfl_xor(ay, 16); ay += __shfl_xor(ay, 32);
        az += __shfl_xor(az, 16); az += __shfl_xor(az, 32);
        aw += __shfl_xor(aw, 16); aw += __shfl_xor(aw, 32);
        // redistribute: lane l takes dim l = comp (l&3) from lane l>>2
        const float sx = __shfl(ax, lane >> 2);
        const float sy = __shfl(ay, lane >> 2);
        const float sz = __shfl(az, lane >> 2);
        const float sw = __shfl(aw, lane >> 2);
        const float ab = (lane & 1) ? sy : sx;
        const float cd = (lane & 1) ? sw : sz;
        const float a = (lane & 2) ? cd : ab;
        const int p = c * 64 + lane;
        unsigned o0, o1;
        threefry2x32(0u, 42u, 0u, (unsigned)p, o0, o1);
        const unsigned bits = o0 ^ o1;
        const float u = __uint_as_float((bits >> 9) | 0x3f800000u) - 1.0f;
        const float h = tanhf(sdinv[nl] * a + bv);
        out[p] = (u < 0.9f) ? h / 0.9f : 0.0f;
    }
}

extern "C" void kernel_launch(void* const* d_in, const int* in_sizes, int n_in,
                              void* d_out, int out_size, void* d_ws, size_t ws_size,
                              hipStream_t stream) {
    const float* x  = (const float*)d_in[0];
    const float* W  = (const float*)d_in[1];
    const float* b  = (const float*)d_in[2];
    const int*   ei = (const int*)d_in[3];
    float* out = (float*)d_out;

    __hip_bfloat16* xsh = (__hip_bfloat16*)d_ws;            // bf16[NN*64]
    unsigned* packed = (unsigned*)(xsh + (size_t)NN * 64);  // u32[NE]
    int* bhist   = (int*)(packed + NE);                     // i32[NBUCK]
    int* bstart  = bhist + NBUCK;                           // i32[NBUCK+1]
    int* bcur    = bstart + NBUCK + 1;                      // i32[NBUCK]
    int* bh_part = bcur + NBUCK;                            // i32[P1B*NBUCK]

    hipMemsetAsync(bhist, 0, NBUCK * sizeof(int), stream);
    k_bhist<<<P1B, P1T, 0, stream>>>(ei, bhist, bh_part);
    k_bscan<<<1, 1024, 0, stream>>>(bhist, bstart, bcur);
    k_p1<<<P1B, P1T, 0, stream>>>(ei, bh_part, bcur, packed);
    k_xw<<<NBUCK, 256, 0, stream>>>(x, W, packed, bstart, xsh);
    k_sagg<<<NBUCK * 2, 256, 0, stream>>>(packed, bstart, xsh, b, out);
}

// Round 19
// 134.922 us; speedup vs baseline: 1.4015x; 1.0727x over previous
//
#include <hip/hip_runtime.h>
#include <hip/hip_bf16.h>

// GCNConv: one-pass fixed-capacity binning (64 tgts/bucket, CAP slots each) ->
// fused per-half-bucket {LDS counting sort + quarter-lane gather + epilogue}.
// agg[c] = dinv[c] * ( xs[c] + sum_{e: col[e]==c} xs[row[e]] ),
//   xs[i] = (x@W)[i] * dinv[i],  dinv[i] = rsqrt(1 + indeg(i))
// out = dropout(tanh(agg + b)), JAX partitionable-threefry key (0,42), p_keep=0.9:
//   bits[p] = o0^o1 of threefry((0,42), 0, p); u = bitcast(bits>>9|0x3f800000)-1; keep = u<0.9.
//
// R8: __shfl only in uniform regions (predicated regions contain loads only).
// R18 lesson: plumbing ~84us >> sagg 60us. R19: delete k_bhist+k_bscan — each
//   bucket owns a fixed CAP=1216 region (mean 1024, +6sigma); k_p1 reserves
//   via one global atomicAdd per (block,bucket). Overflow -> spill list
//   (empty for this input; consumers scan it, graceful for any input).
//
// ws (~20.5 MB): xsh bf16[NN*64] | packed u32[NBUCK*CAP] | gcur i32[NBUCK] |
//                gspill i32[1] | spill_pk u32[SPILLCAP] | spill_bk u32[SPILLCAP]

#define NN 100000
#define NE 1600000
#define NBUCK 1563
#define P1B 128
#define P1T 1024
#define CHUNK 12500         // P1B * CHUNK == NE
#define CAP 1216            // per-bucket region (mean 1024, +6 sigma)
#define SPILLCAP 16384
#define HCAP 1536           // per-half-bucket LDS sort capacity

// ---------------- Threefry2x32 (JAX-exact) ----------------
__device__ __forceinline__ unsigned rotl32(unsigned x, int r) {
    return (x << r) | (x >> (32 - r));
}

__device__ __forceinline__ void threefry2x32(unsigned k0, unsigned k1,
                                             unsigned x0, unsigned x1,
                                             unsigned& o0, unsigned& o1) {
    const unsigned ks0 = k0, ks1 = k1, ks2 = k0 ^ k1 ^ 0x1BD11BDAu;
    x0 += ks0; x1 += ks1;
    x0 += x1; x1 = rotl32(x1, 13); x1 ^= x0;
    x0 += x1; x1 = rotl32(x1, 15); x1 ^= x0;
    x0 += x1; x1 = rotl32(x1, 26); x1 ^= x0;
    x0 += x1; x1 = rotl32(x1, 6);  x1 ^= x0;
    x0 += ks1; x1 += ks2 + 1u;
    x0 += x1; x1 = rotl32(x1, 17); x1 ^= x0;
    x0 += x1; x1 = rotl32(x1, 29); x1 ^= x0;
    x0 += x1; x1 = rotl32(x1, 16); x1 ^= x0;
    x0 += x1; x1 = rotl32(x1, 24); x1 ^= x0;
    x0 += ks2; x1 += ks0 + 2u;
    x0 += x1; x1 = rotl32(x1, 13); x1 ^= x0;
    x0 += x1; x1 = rotl32(x1, 15); x1 ^= x0;
    x0 += x1; x1 = rotl32(x1, 26); x1 ^= x0;
    x0 += x1; x1 = rotl32(x1, 6);  x1 ^= x0;
    x0 += ks0; x1 += ks1 + 3u;
    x0 += x1; x1 = rotl32(x1, 17); x1 ^= x0;
    x0 += x1; x1 = rotl32(x1, 29); x1 ^= x0;
    x0 += x1; x1 = rotl32(x1, 16); x1 ^= x0;
    x0 += x1; x1 = rotl32(x1, 24); x1 ^= x0;
    x0 += ks1; x1 += ks2 + 4u;
    x0 += x1; x1 = rotl32(x1, 13); x1 ^= x0;
    x0 += x1; x1 = rotl32(x1, 15); x1 ^= x0;
    x0 += x1; x1 = rotl32(x1, 26); x1 ^= x0;
    x0 += x1; x1 = rotl32(x1, 6);  x1 ^= x0;
    x0 += ks2; x1 += ks0 + 5u;
    o0 = x0; o1 = x1;
}

// ---------------- Kernels ----------------
// One-pass binning: LDS hist -> one global reserve atomic per (block,bucket)
// -> grouped writes into fixed regions. Overflow -> spill list.
__global__ __launch_bounds__(P1T) void k_p1(const int* __restrict__ ei,
                                            int* __restrict__ gcur,
                                            unsigned* __restrict__ packed,
                                            unsigned* __restrict__ spill_pk,
                                            unsigned* __restrict__ spill_bk,
                                            int* __restrict__ gspill) {
    __shared__ int hb[NBUCK];
    __shared__ int lc[NBUCK];
    const int tid = threadIdx.x;
    for (int i = tid; i < NBUCK; i += P1T) { hb[i] = 0; lc[i] = 0; }
    __syncthreads();
    const int base = blockIdx.x * CHUNK;
    for (int i = tid; i < CHUNK; i += P1T) {
        const unsigned t = (unsigned)ei[NE + base + i];
        if (t < NN) atomicAdd(&hb[t >> 6], 1);
    }
    __syncthreads();
    for (int i = tid; i < NBUCK; i += P1T) {
        const int h = hb[i];
        hb[i] = h ? atomicAdd(&gcur[i], h) : 0;  // reserve (may exceed CAP)
        lc[i] = 0;
    }
    __syncthreads();
    for (int i = tid; i < CHUNK; i += P1T) {
        const unsigned t = (unsigned)ei[NE + base + i];
        if (t >= NN) continue;
        const unsigned src = (unsigned)ei[base + i];
        const int bk = t >> 6;
        const unsigned pk = src | ((t & 63u) << 17);
        const int pos = hb[bk] + atomicAdd(&lc[bk], 1);
        if (pos < CAP) {
            packed[(size_t)bk * CAP + pos] = pk;
        } else {  // rare overflow: graceful spill
            const int sp = atomicAdd(gspill, 1);
            if (sp < SPILLCAP) { spill_pk[sp] = pk; spill_bk[sp] = (unsigned)bk; }
        }
    }
}

// x@W with deg fused: block b == bucket b; hist its region (+spill) -> dinv
// in LDS. W register-resident; x rows staged in LDS, distributed per-row via
// ds_read_b128 broadcasts + 64 register FMAs. 64 rows/block, 16/wave.
__global__ __launch_bounds__(256) void k_xw(const float* __restrict__ x,
                                            const float* __restrict__ W,
                                            const unsigned* __restrict__ packed,
                                            const int* __restrict__ gcur,
                                            const unsigned* __restrict__ spill_pk,
                                            const unsigned* __restrict__ spill_bk,
                                            const int* __restrict__ gspill,
                                            __hip_bfloat16* __restrict__ xsh) {
    __shared__ float Wl[64 * 64];   // 16 KB
    __shared__ float xl[64 * 64];   // 16 KB
    __shared__ int hist[64];
    __shared__ float sdinv[64];
    const int tid = threadIdx.x;
    const int b = blockIdx.x;       // grid == NBUCK
    const int row0 = b * 64;
    for (int i = tid; i < 64 * 64; i += 256) Wl[i] = W[i];  // coalesced
    {
        const int nrow = (NN - row0) < 64 ? (NN - row0) : 64;
        const int nfl4 = nrow * 16;
        const float4* __restrict__ xg = (const float4*)(x + (size_t)row0 * 64);
        float4* __restrict__ xl4 = (float4*)xl;
        for (int i = tid; i < nfl4; i += 256) xl4[i] = xg[i];
    }
    if (tid < 64) hist[tid] = 0;
    __syncthreads();
    {   // degree hist: fixed region + spill (spill empty in practice)
        int cnt = gcur[b];
        cnt = (cnt < 0) ? 0 : (cnt > CAP ? CAP : cnt);
        const unsigned* __restrict__ seg = packed + (size_t)b * CAP;
        for (int i = tid; i < cnt; i += 256) atomicAdd(&hist[seg[i] >> 17], 1);
        int ns = *gspill;
        ns = (ns < 0) ? 0 : (ns > SPILLCAP ? SPILLCAP : ns);
        for (int i = tid; i < ns; i += 256)
            if ((int)spill_bk[i] == b) atomicAdd(&hist[(spill_pk[i] >> 17) & 63u], 1);
    }
    __syncthreads();
    if (tid < 64) sdinv[tid] = rsqrtf(1.0f + (float)hist[tid]);
    __syncthreads();
    const int wid = tid >> 6, lane = tid & 63;
    float wreg[64];
#pragma unroll
    for (int k = 0; k < 64; ++k) wreg[k] = Wl[k * 64 + lane];
    const int rbase = wid * 16;
#pragma unroll 1
    for (int r = 0; r < 16; ++r) {
        const int row = row0 + rbase + r;
        if (row >= NN) break;  // wave-uniform
        const float4* __restrict__ xr4 = (const float4*)(xl + (rbase + r) * 64);
        float sum = 0.0f;
#pragma unroll
        for (int q = 0; q < 16; ++q) {
            const float4 xv = xr4[q];  // ds_read_b128 broadcast
            sum = fmaf(xv.x, wreg[4 * q + 0], sum);
            sum = fmaf(xv.y, wreg[4 * q + 1], sum);
            sum = fmaf(xv.z, wreg[4 * q + 2], sum);
            sum = fmaf(xv.w, wreg[4 * q + 3], sum);
        }
        xsh[(size_t)row * 64 + lane] = __float2bfloat16(sum * sdinv[rbase + r]);
    }
}

// Fused per-HALF-bucket sort + aggregate + epilogue (R15 gather shape).
// 2 blocks/bucket, 32 nodes each. Segment = fixed region + spill (filtered).
__global__ __launch_bounds__(256) void k_sagg(const unsigned* __restrict__ packed,
                                              const int* __restrict__ gcur,
                                              const unsigned* __restrict__ spill_pk,
                                              const unsigned* __restrict__ spill_bk,
                                              const int* __restrict__ gspill,
                                              const __hip_bfloat16* __restrict__ xsh,
                                              const float* __restrict__ bias,
                                              float* __restrict__ out) {
    __shared__ unsigned sorted[HCAP];  // 6 KB
    __shared__ int hist[32];
    __shared__ int pref[32];
    __shared__ int cur[32];
    __shared__ float sdinv[32];
    const int tid = threadIdx.x;
    const int b = blockIdx.x >> 1;         // bucket
    const unsigned half = blockIdx.x & 1;  // 0: tl 0..31, 1: tl 32..63
    int seg = gcur[b];
    seg = (seg < 0) ? 0 : (seg > CAP ? CAP : seg);
    const unsigned* __restrict__ region = packed + (size_t)b * CAP;
    int ns = *gspill;
    ns = (ns < 0) ? 0 : (ns > SPILLCAP ? SPILLCAP : ns);
    if (tid < 32) hist[tid] = 0;
    __syncthreads();
    for (int i = tid; i < seg; i += 256) {
        const unsigned pk = region[i];
        if (((pk >> 22) & 1u) == half) atomicAdd(&hist[(pk >> 17) & 31u], 1);
    }
    for (int i = tid; i < ns; i += 256) {  // spill: empty in practice
        if ((int)spill_bk[i] == b) {
            const unsigned pk = spill_pk[i];
            if (((pk >> 22) & 1u) == half) atomicAdd(&hist[(pk >> 17) & 31u], 1);
        }
    }
    __syncthreads();
    if (tid == 0) {
        int run = 0;
        for (int t = 0; t < 32; ++t) { pref[t] = run; run += hist[t]; }
    }
    __syncthreads();
    const int hcnt = pref[31] + hist[31];
    const bool oversize = (hcnt > HCAP);
    if (tid < 32) {
        cur[tid] = pref[tid];
        sdinv[tid] = rsqrtf(1.0f + (float)hist[tid]);
    }
    __syncthreads();
    if (!oversize) {
        for (int i = tid; i < seg; i += 256) {
            const unsigned pk = region[i];
            if (((pk >> 22) & 1u) == half) {
                const int pos = atomicAdd(&cur[(pk >> 17) & 31u], 1);
                if (pos < HCAP) sorted[pos] = pk & 0x1FFFFu;
            }
        }
        for (int i = tid; i < ns; i += 256) {
            if ((int)spill_bk[i] == b) {
                const unsigned pk = spill_pk[i];
                if (((pk >> 22) & 1u) == half) {
                    const int pos = atomicAdd(&cur[(pk >> 17) & 31u], 1);
                    if (pos < HCAP) sorted[pos] = pk & 0x1FFFFu;
                }
            }
        }
    }
    __syncthreads();

    const int wid = tid >> 6, lane = tid & 63;
    const int q = lane >> 4, sl = lane & 15;   // quarter, dim-quad
    const uint2* __restrict__ xs4 = (const uint2*)xsh;  // 4 bf16 per elem
    const float bv = bias[lane];
#pragma unroll 1
    for (int t = 0; t < 8; ++t) {
        const int nl = wid * 8 + t;            // 0..31 within half
        const int c = b * 64 + (int)half * 32 + nl;
        if (c >= NN) break;  // wave-uniform
        const int off = pref[nl];
        int deg = hist[nl];
        deg = (deg < 0) ? 0 : (deg > hcnt ? hcnt : deg);  // defensive
        float4 a0 = {0.f, 0.f, 0.f, 0.f}, a1 = {0.f, 0.f, 0.f, 0.f};
        if (q == 0) {  // self-loop term (counted once)
            const uint2 v = xs4[(size_t)c * 16 + sl];
            a0.x += __uint_as_float(v.x << 16);
            a0.y += __uint_as_float(v.x & 0xffff0000u);
            a0.z += __uint_as_float(v.y << 16);
            a0.w += __uint_as_float(v.y & 0xffff0000u);
        }
        if (!oversize) {
            int j = 0;
            for (; j + 7 < deg; j += 8) {  // 8 edges: 2 chains x 4 quarters
                const int s0 = (int)sorted[off + j + q];
                const int s1 = (int)sorted[off + j + 4 + q];
                const uint2 v0 = xs4[(size_t)s0 * 16 + sl];
                const uint2 v1 = xs4[(size_t)s1 * 16 + sl];
                a0.x += __uint_as_float(v0.x << 16); a0.y += __uint_as_float(v0.x & 0xffff0000u);
                a0.z += __uint_as_float(v0.y << 16); a0.w += __uint_as_float(v0.y & 0xffff0000u);
                a1.x += __uint_as_float(v1.x << 16); a1.y += __uint_as_float(v1.x & 0xffff0000u);
                a1.z += __uint_as_float(v1.y << 16); a1.w += __uint_as_float(v1.y & 0xffff0000u);
            }
            for (; j < deg; j += 4) {  // tail: predicated loads, no shfl
                const int eo = j + q;
                if (eo < deg) {
                    const int s0 = (int)sorted[off + eo];
                    const uint2 v = xs4[(size_t)s0 * 16 + sl];
                    a0.x += __uint_as_float(v.x << 16);
                    a0.y += __uint_as_float(v.x & 0xffff0000u);
                    a0.z += __uint_as_float(v.y << 16);
                    a0.w += __uint_as_float(v.y & 0xffff0000u);
                }
            }
        } else {  // scan-mode fallback: region + spill, tl-tagged
            if (q == 0) {
                const unsigned tl = (unsigned)((int)half * 32 + nl);
                for (int i = 0; i < seg; ++i) {
                    const unsigned pk = region[i];
                    if ((pk >> 17) == tl) {
                        const uint2 v = xs4[(size_t)(pk & 0x1FFFFu) * 16 + sl];
                        a0.x += __uint_as_float(v.x << 16);
                        a0.y += __uint_as_float(v.x & 0xffff0000u);
                        a0.z += __uint_as_float(v.y << 16);
                        a0.w += __uint_as_float(v.y & 0xffff0000u);
                    }
                }
                for (int i = 0; i < ns; ++i) {
                    if ((int)spill_bk[i] == b) {
                        const unsigned pk = spill_pk[i];
                        if ((pk >> 17) == tl) {
                            const uint2 v = xs4[(size_t)(pk & 0x1FFFFu) * 16 + sl];
                            a0.x += __uint_as_float(v.x << 16);
                            a0.y += __uint_as_float(v.x & 0xffff0000u);
                            a0.z += __uint_as_float(v.y << 16);
                            a0.w += __uint_as_float(v.y & 0xffff0000u);
                        }
                    }
                }
            }
        }
        // combine chains, then quarters (uniform shfls, all lanes active)
        float ax = a0.x + a1.x, ay = a0.y + a1.y;
        float az = a0.z + a1.z, aw = a0.w + a1.w;
        ax += __shfl_xor(ax, 16); ax += __shfl_xor(ax, 32);
        ay += __shfl_xor(ay, 16); ay += __shfl_xor(ay, 32);
        az += __shfl_xor(az, 16); az += __shfl_xor(az, 32);
        aw += __shfl_xor(aw, 16); aw += __shfl_xor(aw, 32);
        // redistribute: lane l takes dim l = comp (l&3) from lane l>>2
        const float sx = __shfl(ax, lane >> 2);
        const float sy = __shfl(ay, lane >> 2);
        const float sz = __shfl(az, lane >> 2);
        const float sw = __shfl(aw, lane >> 2);
        const float ab = (lane & 1) ? sy : sx;
        const float cd = (lane & 1) ? sw : sz;
        const float a = (lane & 2) ? cd : ab;
        const int p = c * 64 + lane;
        unsigned o0, o1;
        threefry2x32(0u, 42u, 0u, (unsigned)p, o0, o1);
        const unsigned bits = o0 ^ o1;
        const float u = __uint_as_float((bits >> 9) | 0x3f800000u) - 1.0f;
        const float h = tanhf(sdinv[nl] * a + bv);
        out[p] = (u < 0.9f) ? h / 0.9f : 0.0f;
    }
}

extern "C" void kernel_launch(void* const* d_in, const int* in_sizes, int n_in,
                              void* d_out, int out_size, void* d_ws, size_t ws_size,
                              hipStream_t stream) {
    const float* x  = (const float*)d_in[0];
    const float* W  = (const float*)d_in[1];
    const float* b  = (const float*)d_in[2];
    const int*   ei = (const int*)d_in[3];
    float* out = (float*)d_out;

    __hip_bfloat16* xsh = (__hip_bfloat16*)d_ws;              // bf16[NN*64]
    unsigned* packed = (unsigned*)(xsh + (size_t)NN * 64);    // u32[NBUCK*CAP]
    int* gcur = (int*)(packed + (size_t)NBUCK * CAP);         // i32[NBUCK]
    int* gspill = gcur + NBUCK;                               // i32[1]
    unsigned* spill_pk = (unsigned*)(gspill + 1);             // u32[SPILLCAP]
    unsigned* spill_bk = spill_pk + SPILLCAP;                 // u32[SPILLCAP]

    hipMemsetAsync(gcur, 0, (NBUCK + 1) * sizeof(int), stream);
    k_p1<<<P1B, P1T, 0, stream>>>(ei, gcur, packed, spill_pk, spill_bk, gspill);
    k_xw<<<NBUCK, 256, 0, stream>>>(x, W, packed, gcur, spill_pk, spill_bk, gspill, xsh);
    k_sagg<<<NBUCK * 2, 256, 0, stream>>>(packed, gcur, spill_pk, spill_bk, gspill, xsh, b, out);
}

// Round 20
// 125.861 us; speedup vs baseline: 1.5024x; 1.0720x over previous
//
#include <hip/hip_runtime.h>
#include <hip/hip_bf16.h>

// GCNConv: one-pass fixed-capacity binning (64 tgts/bucket, CAP slots each) ->
// fused per-half-bucket {LDS counting sort + quarter-lane gather + epilogue}.
// agg[c] = dinv[c] * ( xs[c] + sum_{e: col[e]==c} xs[row[e]] ),
//   xs[i] = (x@W)[i] * dinv[i],  dinv[i] = rsqrt(1 + indeg(i))
// out = dropout(tanh(agg + b)), JAX partitionable-threefry key (0,42), p_keep=0.9:
//   bits[p] = o0^o1 of threefry((0,42), 0, p); u = bitcast(bits>>9|0x3f800000)-1; keep = u<0.9.
//
// R8: __shfl only in uniform regions (predicated regions contain loads only).
// R19: fixed-CAP regions deleted bhist/bscan -> 134.9us; p1+xw ~71us remain.
// R20: (a) k_xw lane=row — x staged [64][65] padded (2 lanes/bank = free),
//   W via wave-uniform SCALAR loads (s_load + SGPR-src FMA), LDS instrs /64;
//   (b) k_p1 256 blocks (full CU coverage), CHUNK 6250.
//
// ws (~20.5 MB): xsh bf16[NN*64] | packed u32[NBUCK*CAP] | gcur i32[NBUCK] |
//                gspill i32[1] | spill_pk u32[SPILLCAP] | spill_bk u32[SPILLCAP]

#define NN 100000
#define NE 1600000
#define NBUCK 1563
#define P1B 256
#define P1T 1024
#define CHUNK 6250          // P1B * CHUNK == NE
#define CAP 1216            // per-bucket region (mean 1024, +6 sigma)
#define SPILLCAP 16384
#define HCAP 1536           // per-half-bucket LDS sort capacity

// ---------------- Threefry2x32 (JAX-exact) ----------------
__device__ __forceinline__ unsigned rotl32(unsigned x, int r) {
    return (x << r) | (x >> (32 - r));
}

__device__ __forceinline__ void threefry2x32(unsigned k0, unsigned k1,
                                             unsigned x0, unsigned x1,
                                             unsigned& o0, unsigned& o1) {
    const unsigned ks0 = k0, ks1 = k1, ks2 = k0 ^ k1 ^ 0x1BD11BDAu;
    x0 += ks0; x1 += ks1;
    x0 += x1; x1 = rotl32(x1, 13); x1 ^= x0;
    x0 += x1; x1 = rotl32(x1, 15); x1 ^= x0;
    x0 += x1; x1 = rotl32(x1, 26); x1 ^= x0;
    x0 += x1; x1 = rotl32(x1, 6);  x1 ^= x0;
    x0 += ks1; x1 += ks2 + 1u;
    x0 += x1; x1 = rotl32(x1, 17); x1 ^= x0;
    x0 += x1; x1 = rotl32(x1, 29); x1 ^= x0;
    x0 += x1; x1 = rotl32(x1, 16); x1 ^= x0;
    x0 += x1; x1 = rotl32(x1, 24); x1 ^= x0;
    x0 += ks2; x1 += ks0 + 2u;
    x0 += x1; x1 = rotl32(x1, 13); x1 ^= x0;
    x0 += x1; x1 = rotl32(x1, 15); x1 ^= x0;
    x0 += x1; x1 = rotl32(x1, 26); x1 ^= x0;
    x0 += x1; x1 = rotl32(x1, 6);  x1 ^= x0;
    x0 += ks0; x1 += ks1 + 3u;
    x0 += x1; x1 = rotl32(x1, 17); x1 ^= x0;
    x0 += x1; x1 = rotl32(x1, 29); x1 ^= x0;
    x0 += x1; x1 = rotl32(x1, 16); x1 ^= x0;
    x0 += x1; x1 = rotl32(x1, 24); x1 ^= x0;
    x0 += ks1; x1 += ks2 + 4u;
    x0 += x1; x1 = rotl32(x1, 13); x1 ^= x0;
    x0 += x1; x1 = rotl32(x1, 15); x1 ^= x0;
    x0 += x1; x1 = rotl32(x1, 26); x1 ^= x0;
    x0 += x1; x1 = rotl32(x1, 6);  x1 ^= x0;
    x0 += ks2; x1 += ks0 + 5u;
    o0 = x0; o1 = x1;
}

// ---------------- Kernels ----------------
// One-pass binning: LDS hist -> one global reserve atomic per (block,bucket)
// -> grouped writes into fixed regions. Overflow -> spill list.
__global__ __launch_bounds__(P1T) void k_p1(const int* __restrict__ ei,
                                            int* __restrict__ gcur,
                                            unsigned* __restrict__ packed,
                                            unsigned* __restrict__ spill_pk,
                                            unsigned* __restrict__ spill_bk,
                                            int* __restrict__ gspill) {
    __shared__ int hb[NBUCK];
    __shared__ int lc[NBUCK];
    const int tid = threadIdx.x;
    for (int i = tid; i < NBUCK; i += P1T) { hb[i] = 0; lc[i] = 0; }
    __syncthreads();
    const int base = blockIdx.x * CHUNK;
    for (int i = tid; i < CHUNK; i += P1T) {
        const unsigned t = (unsigned)ei[NE + base + i];
        if (t < NN) atomicAdd(&hb[t >> 6], 1);
    }
    __syncthreads();
    for (int i = tid; i < NBUCK; i += P1T) {
        const int h = hb[i];
        hb[i] = h ? atomicAdd(&gcur[i], h) : 0;  // reserve (may exceed CAP)
        lc[i] = 0;
    }
    __syncthreads();
    for (int i = tid; i < CHUNK; i += P1T) {
        const unsigned t = (unsigned)ei[NE + base + i];
        if (t >= NN) continue;
        const unsigned src = (unsigned)ei[base + i];
        const int bk = t >> 6;
        const unsigned pk = src | ((t & 63u) << 17);
        const int pos = hb[bk] + atomicAdd(&lc[bk], 1);
        if (pos < CAP) {
            packed[(size_t)bk * CAP + pos] = pk;
        } else {  // rare overflow: graceful spill
            const int sp = atomicAdd(gspill, 1);
            if (sp < SPILLCAP) { spill_pk[sp] = pk; spill_bk[sp] = (unsigned)bk; }
        }
    }
}

// x@W, lane=row: one 64-thread wave per bucket (64 rows). x staged in padded
// LDS [64][65] (per-lane reads 2 lanes/bank = free); W read via WAVE-UNIFORM
// scalar loads (s_load + SGPR-operand FMA) — LDS instructions cut 64x vs R19.
// deg hist fused (region + spill); transposed store bounced through LDS.
__global__ __launch_bounds__(64) void k_xw(const float* __restrict__ x,
                                           const float* __restrict__ W,
                                           const unsigned* __restrict__ packed,
                                           const int* __restrict__ gcur,
                                           const unsigned* __restrict__ spill_pk,
                                           const unsigned* __restrict__ spill_bk,
                                           const int* __restrict__ gspill,
                                           __hip_bfloat16* __restrict__ xsh) {
    __shared__ float xl[64 * 65];   // 16.64 KB (reused as out-bounce)
    __shared__ int hist[64];
    const int lane = threadIdx.x;   // block == 1 wave; lane == local row
    const int b = blockIdx.x;       // bucket; rows [64b, 64b+64)
    const int row0 = b * 64;
    const int nrow = (NN - row0) < 64 ? (NN - row0) : 64;
    {   // stage x rows, coalesced float4; LDS row stride 65 floats
        const float4* __restrict__ xg = (const float4*)(x + (size_t)row0 * 64);
        const int nf4 = nrow * 16;
        for (int i = lane; i < nf4; i += 64) {
            const int r = i >> 4, q = i & 15;
            *(float4*)&xl[r * 65 + 4 * q] = xg[i];
        }
    }
    hist[lane] = 0;
    __syncthreads();
    {   // degree hist: fixed region + spill (spill empty in practice)
        int cnt = gcur[b];
        cnt = (cnt < 0) ? 0 : (cnt > CAP ? CAP : cnt);
        const unsigned* __restrict__ seg = packed + (size_t)b * CAP;
        for (int i = lane; i < cnt; i += 64) atomicAdd(&hist[seg[i] >> 17], 1);
        int ns = *gspill;
        ns = (ns < 0) ? 0 : (ns > SPILLCAP ? SPILLCAP : ns);
        for (int i = lane; i < ns; i += 64)
            if ((int)spill_bk[i] == b) atomicAdd(&hist[(spill_pk[i] >> 17) & 63u], 1);
    }
    __syncthreads();
    const float dv = rsqrtf(1.0f + (float)hist[lane]);  // this lane's row
    float acc[64];
#pragma unroll
    for (int d = 0; d < 64; ++d) acc[d] = 0.0f;
#pragma unroll 1
    for (int k = 0; k < 64; ++k) {
        const float xv = xl[lane * 65 + k];  // per-lane, (lane+k)%32 banks
#pragma unroll
        for (int d = 0; d < 64; ++d)         // W[k*64+d] is wave-uniform ->
            acc[d] = fmaf(xv, W[k * 64 + d], acc[d]);  // s_load + SGPR FMA
    }
    __syncthreads();  // xl reuse as bounce buffer
    unsigned* __restrict__ ol = (unsigned*)xl;  // [64][33] packed bf16 pairs
#pragma unroll
    for (int q = 0; q < 32; ++q) {
        const __hip_bfloat16 b0 = __float2bfloat16(acc[2 * q] * dv);
        const __hip_bfloat16 b1 = __float2bfloat16(acc[2 * q + 1] * dv);
        const unsigned w = ((unsigned)*(const unsigned short*)&b1 << 16) |
                           *(const unsigned short*)&b0;
        ol[lane * 33 + q] = w;  // bank (lane+q)%32: 2-way, free
    }
    __syncthreads();
    unsigned* __restrict__ og = (unsigned*)(xsh + (size_t)row0 * 64);
    const int nw = nrow * 32;
    for (int i = lane; i < nw; i += 64) {  // coalesced global store
        const int r = i >> 5, q = i & 31;
        og[i] = ol[r * 33 + q];
    }
}

// Fused per-HALF-bucket sort + aggregate + epilogue (R15 gather shape).
// 2 blocks/bucket, 32 nodes each. Segment = fixed region + spill (filtered).
__global__ __launch_bounds__(256) void k_sagg(const unsigned* __restrict__ packed,
                                              const int* __restrict__ gcur,
                                              const unsigned* __restrict__ spill_pk,
                                              const unsigned* __restrict__ spill_bk,
                                              const int* __restrict__ gspill,
                                              const __hip_bfloat16* __restrict__ xsh,
                                              const float* __restrict__ bias,
                                              float* __restrict__ out) {
    __shared__ unsigned sorted[HCAP];  // 6 KB
    __shared__ int hist[32];
    __shared__ int pref[32];
    __shared__ int cur[32];
    __shared__ float sdinv[32];
    const int tid = threadIdx.x;
    const int b = blockIdx.x >> 1;         // bucket
    const unsigned half = blockIdx.x & 1;  // 0: tl 0..31, 1: tl 32..63
    int seg = gcur[b];
    seg = (seg < 0) ? 0 : (seg > CAP ? CAP : seg);
    const unsigned* __restrict__ region = packed + (size_t)b * CAP;
    int ns = *gspill;
    ns = (ns < 0) ? 0 : (ns > SPILLCAP ? SPILLCAP : ns);
    if (tid < 32) hist[tid] = 0;
    __syncthreads();
    for (int i = tid; i < seg; i += 256) {
        const unsigned pk = region[i];
        if (((pk >> 22) & 1u) == half) atomicAdd(&hist[(pk >> 17) & 31u], 1);
    }
    for (int i = tid; i < ns; i += 256) {  // spill: empty in practice
        if ((int)spill_bk[i] == b) {
            const unsigned pk = spill_pk[i];
            if (((pk >> 22) & 1u) == half) atomicAdd(&hist[(pk >> 17) & 31u], 1);
        }
    }
    __syncthreads();
    if (tid == 0) {
        int run = 0;
        for (int t = 0; t < 32; ++t) { pref[t] = run; run += hist[t]; }
    }
    __syncthreads();
    const int hcnt = pref[31] + hist[31];
    const bool oversize = (hcnt > HCAP);
    if (tid < 32) {
        cur[tid] = pref[tid];
        sdinv[tid] = rsqrtf(1.0f + (float)hist[tid]);
    }
    __syncthreads();
    if (!oversize) {
        for (int i = tid; i < seg; i += 256) {
            const unsigned pk = region[i];
            if (((pk >> 22) & 1u) == half) {
                const int pos = atomicAdd(&cur[(pk >> 17) & 31u], 1);
                if (pos < HCAP) sorted[pos] = pk & 0x1FFFFu;
            }
        }
        for (int i = tid; i < ns; i += 256) {
            if ((int)spill_bk[i] == b) {
                const unsigned pk = spill_pk[i];
                if (((pk >> 22) & 1u) == half) {
                    const int pos = atomicAdd(&cur[(pk >> 17) & 31u], 1);
                    if (pos < HCAP) sorted[pos] = pk & 0x1FFFFu;
                }
            }
        }
    }
    __syncthreads();

    const int wid = tid >> 6, lane = tid & 63;
    const int q = lane >> 4, sl = lane & 15;   // quarter, dim-quad
    const uint2* __restrict__ xs4 = (const uint2*)xsh;  // 4 bf16 per elem
    const float bv = bias[lane];
#pragma unroll 1
    for (int t = 0; t < 8; ++t) {
        const int nl = wid * 8 + t;            // 0..31 within half
        const int c = b * 64 + (int)half * 32 + nl;
        if (c >= NN) break;  // wave-uniform
        const int off = pref[nl];
        int deg = hist[nl];
        deg = (deg < 0) ? 0 : (deg > hcnt ? hcnt : deg);  // defensive
        float4 a0 = {0.f, 0.f, 0.f, 0.f}, a1 = {0.f, 0.f, 0.f, 0.f};
        if (q == 0) {  // self-loop term (counted once)
            const uint2 v = xs4[(size_t)c * 16 + sl];
            a0.x += __uint_as_float(v.x << 16);
            a0.y += __uint_as_float(v.x & 0xffff0000u);
            a0.z += __uint_as_float(v.y << 16);
            a0.w += __uint_as_float(v.y & 0xffff0000u);
        }
        if (!oversize) {
            int j = 0;
            for (; j + 7 < deg; j += 8) {  // 8 edges: 2 chains x 4 quarters
                const int s0 = (int)sorted[off + j + q];
                const int s1 = (int)sorted[off + j + 4 + q];
                const uint2 v0 = xs4[(size_t)s0 * 16 + sl];
                const uint2 v1 = xs4[(size_t)s1 * 16 + sl];
                a0.x += __uint_as_float(v0.x << 16); a0.y += __uint_as_float(v0.x & 0xffff0000u);
                a0.z += __uint_as_float(v0.y << 16); a0.w += __uint_as_float(v0.y & 0xffff0000u);
                a1.x += __uint_as_float(v1.x << 16); a1.y += __uint_as_float(v1.x & 0xffff0000u);
                a1.z += __uint_as_float(v1.y << 16); a1.w += __uint_as_float(v1.y & 0xffff0000u);
            }
            for (; j < deg; j += 4) {  // tail: predicated loads, no shfl
                const int eo = j + q;
                if (eo < deg) {
                    const int s0 = (int)sorted[off + eo];
                    const uint2 v = xs4[(size_t)s0 * 16 + sl];
                    a0.x += __uint_as_float(v.x << 16);
                    a0.y += __uint_as_float(v.x & 0xffff0000u);
                    a0.z += __uint_as_float(v.y << 16);
                    a0.w += __uint_as_float(v.y & 0xffff0000u);
                }
            }
        } else {  // scan-mode fallback: region + spill, tl-tagged
            if (q == 0) {
                const unsigned tl = (unsigned)((int)half * 32 + nl);
                for (int i = 0; i < seg; ++i) {
                    const unsigned pk = region[i];
                    if ((pk >> 17) == tl) {
                        const uint2 v = xs4[(size_t)(pk & 0x1FFFFu) * 16 + sl];
                        a0.x += __uint_as_float(v.x << 16);
                        a0.y += __uint_as_float(v.x & 0xffff0000u);
                        a0.z += __uint_as_float(v.y << 16);
                        a0.w += __uint_as_float(v.y & 0xffff0000u);
                    }
                }
                for (int i = 0; i < ns; ++i) {
                    if ((int)spill_bk[i] == b) {
                        const unsigned pk = spill_pk[i];
                        if ((pk >> 17) == tl) {
                            const uint2 v = xs4[(size_t)(pk & 0x1FFFFu) * 16 + sl];
                            a0.x += __uint_as_float(v.x << 16);
                            a0.y += __uint_as_float(v.x & 0xffff0000u);
                            a0.z += __uint_as_float(v.y << 16);
                            a0.w += __uint_as_float(v.y & 0xffff0000u);
                        }
                    }
                }
            }
        }
        // combine chains, then quarters (uniform shfls, all lanes active)
        float ax = a0.x + a1.x, ay = a0.y + a1.y;
        float az = a0.z + a1.z, aw = a0.w + a1.w;
        ax += __shfl_xor(ax, 16); ax += __shfl_xor(ax, 32);
        ay += __shfl_xor(ay, 16); ay += __shfl_xor(ay, 32);
        az += __shfl_xor(az, 16); az += __shfl_xor(az, 32);
        aw += __shfl_xor(aw, 16); aw += __shfl_xor(aw, 32);
        // redistribute: lane l takes dim l = comp (l&3) from lane l>>2
        const float sx = __shfl(ax, lane >> 2);
        const float sy = __shfl(ay, lane >> 2);
        const float sz = __shfl(az, lane >> 2);
        const float sw = __shfl(aw, lane >> 2);
        const float ab = (lane & 1) ? sy : sx;
        const float cd = (lane & 1) ? sw : sz;
        const float a = (lane & 2) ? cd : ab;
        const int p = c * 64 + lane;
        unsigned o0, o1;
        threefry2x32(0u, 42u, 0u, (unsigned)p, o0, o1);
        const unsigned bits = o0 ^ o1;
        const float u = __uint_as_float((bits >> 9) | 0x3f800000u) - 1.0f;
        const float h = tanhf(sdinv[nl] * a + bv);
        out[p] = (u < 0.9f) ? h / 0.9f : 0.0f;
    }
}

extern "C" void kernel_launch(void* const* d_in, const int* in_sizes, int n_in,
                              void* d_out, int out_size, void* d_ws, size_t ws_size,
                              hipStream_t stream) {
    const float* x  = (const float*)d_in[0];
    const float* W  = (const float*)d_in[1];
    const float* b  = (const float*)d_in[2];
    const int*   ei = (const int*)d_in[3];
    float* out = (float*)d_out;

    __hip_bfloat16* xsh = (__hip_bfloat16*)d_ws;              // bf16[NN*64]
    unsigned* packed = (unsigned*)(xsh + (size_t)NN * 64);    // u32[NBUCK*CAP]
    int* gcur = (int*)(packed + (size_t)NBUCK * CAP);         // i32[NBUCK]
    int* gspill = gcur + NBUCK;                               // i32[1]
    unsigned* spill_pk = (unsigned*)(gspill + 1);             // u32[SPILLCAP]
    unsigned* spill_bk = spill_pk + SPILLCAP;                 // u32[SPILLCAP]

    hipMemsetAsync(gcur, 0, (NBUCK + 1) * sizeof(int), stream);
    k_p1<<<P1B, P1T, 0, stream>>>(ei, gcur, packed, spill_pk, spill_bk, gspill);
    k_xw<<<NBUCK, 64, 0, stream>>>(x, W, packed, gcur, spill_pk, spill_bk, gspill, xsh);
    k_sagg<<<NBUCK * 2, 256, 0, stream>>>(packed, gcur, spill_pk, spill_bk, gspill, xsh, b, out);
}

// Round 21
// 116.768 us; speedup vs baseline: 1.6194x; 1.0779x over previous
//
#include <hip/hip_runtime.h>
#include <hip/hip_bf16.h>

// GCNConv: one-pass fixed-capacity binning (64 tgts/bucket, CAP slots each) ->
// fused per-half-bucket {LDS counting sort + node-pair quarter-lane gather +
// epilogue}. No fp32 global atomics anywhere.
// agg[c] = dinv[c] * ( xs[c] + sum_{e: col[e]==c} xs[row[e]] ),
//   xs[i] = (x@W)[i] * dinv[i],  dinv[i] = rsqrt(1 + indeg(i))
// out = dropout(tanh(agg + b)), JAX partitionable-threefry key (0,42), p_keep=0.9:
//   bits[p] = o0^o1 of threefry((0,42), 0, p); u = bitcast(bits>>9|0x3f800000)-1; keep = u<0.9.
//
// R8: __shfl only in uniform regions (predicated regions contain loads only).
// R20: xw lane=row + scalar W; p1 256 blocks -> 125.9us, sagg 65us dominant.
// R21: sagg gathers TWO nodes per iteration (4 chains, 4 loads in flight =
//   2x per-wave MLP at unchanged 128B-row access shape; R16's footprint
//   mistake avoided). Loop bound max(degA,degB) wave-uniform.
//
// ws (~20.5 MB): xsh bf16[NN*64] | packed u32[NBUCK*CAP] | gcur i32[NBUCK] |
//                gspill i32[1] | spill_pk u32[SPILLCAP] | spill_bk u32[SPILLCAP]

#define NN 100000
#define NE 1600000
#define NBUCK 1563
#define P1B 256
#define P1T 1024
#define CHUNK 6250          // P1B * CHUNK == NE
#define CAP 1216            // per-bucket region (mean 1024, +6 sigma)
#define SPILLCAP 16384
#define HCAP 1536           // per-half-bucket LDS sort capacity

// ---------------- Threefry2x32 (JAX-exact) ----------------
__device__ __forceinline__ unsigned rotl32(unsigned x, int r) {
    return (x << r) | (x >> (32 - r));
}

__device__ __forceinline__ void threefry2x32(unsigned k0, unsigned k1,
                                             unsigned x0, unsigned x1,
                                             unsigned& o0, unsigned& o1) {
    const unsigned ks0 = k0, ks1 = k1, ks2 = k0 ^ k1 ^ 0x1BD11BDAu;
    x0 += ks0; x1 += ks1;
    x0 += x1; x1 = rotl32(x1, 13); x1 ^= x0;
    x0 += x1; x1 = rotl32(x1, 15); x1 ^= x0;
    x0 += x1; x1 = rotl32(x1, 26); x1 ^= x0;
    x0 += x1; x1 = rotl32(x1, 6);  x1 ^= x0;
    x0 += ks1; x1 += ks2 + 1u;
    x0 += x1; x1 = rotl32(x1, 17); x1 ^= x0;
    x0 += x1; x1 = rotl32(x1, 29); x1 ^= x0;
    x0 += x1; x1 = rotl32(x1, 16); x1 ^= x0;
    x0 += x1; x1 = rotl32(x1, 24); x1 ^= x0;
    x0 += ks2; x1 += ks0 + 2u;
    x0 += x1; x1 = rotl32(x1, 13); x1 ^= x0;
    x0 += x1; x1 = rotl32(x1, 15); x1 ^= x0;
    x0 += x1; x1 = rotl32(x1, 26); x1 ^= x0;
    x0 += x1; x1 = rotl32(x1, 6);  x1 ^= x0;
    x0 += ks0; x1 += ks1 + 3u;
    x0 += x1; x1 = rotl32(x1, 17); x1 ^= x0;
    x0 += x1; x1 = rotl32(x1, 29); x1 ^= x0;
    x0 += x1; x1 = rotl32(x1, 16); x1 ^= x0;
    x0 += x1; x1 = rotl32(x1, 24); x1 ^= x0;
    x0 += ks1; x1 += ks2 + 4u;
    x0 += x1; x1 = rotl32(x1, 13); x1 ^= x0;
    x0 += x1; x1 = rotl32(x1, 15); x1 ^= x0;
    x0 += x1; x1 = rotl32(x1, 26); x1 ^= x0;
    x0 += x1; x1 = rotl32(x1, 6);  x1 ^= x0;
    x0 += ks2; x1 += ks0 + 5u;
    o0 = x0; o1 = x1;
}

// Per-node epilogue: quarter-reduce, redistribute, tanh + threefry dropout.
// Contains shfls — call ONLY under wave-uniform control flow.
__device__ __forceinline__ void sagg_finish(float4 a0, float4 a1, int lane,
                                            int c, float dv, float bv,
                                            float* __restrict__ out) {
    float ax = a0.x + a1.x, ay = a0.y + a1.y;
    float az = a0.z + a1.z, aw = a0.w + a1.w;
    ax += __shfl_xor(ax, 16); ax += __shfl_xor(ax, 32);
    ay += __shfl_xor(ay, 16); ay += __shfl_xor(ay, 32);
    az += __shfl_xor(az, 16); az += __shfl_xor(az, 32);
    aw += __shfl_xor(aw, 16); aw += __shfl_xor(aw, 32);
    const float sx = __shfl(ax, lane >> 2);
    const float sy = __shfl(ay, lane >> 2);
    const float sz = __shfl(az, lane >> 2);
    const float sw = __shfl(aw, lane >> 2);
    const float ab = (lane & 1) ? sy : sx;
    const float cd = (lane & 1) ? sw : sz;
    const float a = (lane & 2) ? cd : ab;
    const int p = c * 64 + lane;
    unsigned o0, o1;
    threefry2x32(0u, 42u, 0u, (unsigned)p, o0, o1);
    const unsigned bits = o0 ^ o1;
    const float u = __uint_as_float((bits >> 9) | 0x3f800000u) - 1.0f;
    const float h = tanhf(dv * a + bv);
    out[p] = (u < 0.9f) ? h / 0.9f : 0.0f;
}

#define UNPK4(v, A)                                                    \
    A.x += __uint_as_float((v).x << 16);                               \
    A.y += __uint_as_float((v).x & 0xffff0000u);                       \
    A.z += __uint_as_float((v).y << 16);                               \
    A.w += __uint_as_float((v).y & 0xffff0000u);

// ---------------- Kernels ----------------
// One-pass binning: LDS hist -> one global reserve atomic per (block,bucket)
// -> grouped writes into fixed regions. Overflow -> spill list.
__global__ __launch_bounds__(P1T) void k_p1(const int* __restrict__ ei,
                                            int* __restrict__ gcur,
                                            unsigned* __restrict__ packed,
                                            unsigned* __restrict__ spill_pk,
                                            unsigned* __restrict__ spill_bk,
                                            int* __restrict__ gspill) {
    __shared__ int hb[NBUCK];
    __shared__ int lc[NBUCK];
    const int tid = threadIdx.x;
    for (int i = tid; i < NBUCK; i += P1T) { hb[i] = 0; lc[i] = 0; }
    __syncthreads();
    const int base = blockIdx.x * CHUNK;
    for (int i = tid; i < CHUNK; i += P1T) {
        const unsigned t = (unsigned)ei[NE + base + i];
        if (t < NN) atomicAdd(&hb[t >> 6], 1);
    }
    __syncthreads();
    for (int i = tid; i < NBUCK; i += P1T) {
        const int h = hb[i];
        hb[i] = h ? atomicAdd(&gcur[i], h) : 0;  // reserve (may exceed CAP)
        lc[i] = 0;
    }
    __syncthreads();
    for (int i = tid; i < CHUNK; i += P1T) {
        const unsigned t = (unsigned)ei[NE + base + i];
        if (t >= NN) continue;
        const unsigned src = (unsigned)ei[base + i];
        const int bk = t >> 6;
        const unsigned pk = src | ((t & 63u) << 17);
        const int pos = hb[bk] + atomicAdd(&lc[bk], 1);
        if (pos < CAP) {
            packed[(size_t)bk * CAP + pos] = pk;
        } else {  // rare overflow: graceful spill
            const int sp = atomicAdd(gspill, 1);
            if (sp < SPILLCAP) { spill_pk[sp] = pk; spill_bk[sp] = (unsigned)bk; }
        }
    }
}

// x@W, lane=row: one 64-thread wave per bucket (64 rows). x staged in padded
// LDS [64][65]; W via wave-uniform scalar loads (s_load + SGPR-operand FMA).
// deg hist fused (region + spill); transposed store bounced through LDS.
__global__ __launch_bounds__(64) void k_xw(const float* __restrict__ x,
                                           const float* __restrict__ W,
                                           const unsigned* __restrict__ packed,
                                           const int* __restrict__ gcur,
                                           const unsigned* __restrict__ spill_pk,
                                           const unsigned* __restrict__ spill_bk,
                                           const int* __restrict__ gspill,
                                           __hip_bfloat16* __restrict__ xsh) {
    __shared__ float xl[64 * 65];   // 16.64 KB (reused as out-bounce)
    __shared__ int hist[64];
    const int lane = threadIdx.x;   // block == 1 wave; lane == local row
    const int b = blockIdx.x;       // bucket; rows [64b, 64b+64)
    const int row0 = b * 64;
    const int nrow = (NN - row0) < 64 ? (NN - row0) : 64;
    {   // stage x rows, coalesced float4; LDS row stride 65 floats
        const float4* __restrict__ xg = (const float4*)(x + (size_t)row0 * 64);
        const int nf4 = nrow * 16;
        for (int i = lane; i < nf4; i += 64) {
            const int r = i >> 4, q = i & 15;
            *(float4*)&xl[r * 65 + 4 * q] = xg[i];
        }
    }
    hist[lane] = 0;
    __syncthreads();
    {   // degree hist: fixed region + spill (spill empty in practice)
        int cnt = gcur[b];
        cnt = (cnt < 0) ? 0 : (cnt > CAP ? CAP : cnt);
        const unsigned* __restrict__ seg = packed + (size_t)b * CAP;
        for (int i = lane; i < cnt; i += 64) atomicAdd(&hist[seg[i] >> 17], 1);
        int ns = *gspill;
        ns = (ns < 0) ? 0 : (ns > SPILLCAP ? SPILLCAP : ns);
        for (int i = lane; i < ns; i += 64)
            if ((int)spill_bk[i] == b) atomicAdd(&hist[(spill_pk[i] >> 17) & 63u], 1);
    }
    __syncthreads();
    const float dv = rsqrtf(1.0f + (float)hist[lane]);  // this lane's row
    float acc[64];
#pragma unroll
    for (int d = 0; d < 64; ++d) acc[d] = 0.0f;
#pragma unroll 1
    for (int k = 0; k < 64; ++k) {
        const float xv = xl[lane * 65 + k];  // per-lane, (lane+k)%32 banks
#pragma unroll
        for (int d = 0; d < 64; ++d)         // W[k*64+d] is wave-uniform ->
            acc[d] = fmaf(xv, W[k * 64 + d], acc[d]);  // s_load + SGPR FMA
    }
    __syncthreads();  // xl reuse as bounce buffer
    unsigned* __restrict__ ol = (unsigned*)xl;  // [64][33] packed bf16 pairs
#pragma unroll
    for (int q = 0; q < 32; ++q) {
        const __hip_bfloat16 b0 = __float2bfloat16(acc[2 * q] * dv);
        const __hip_bfloat16 b1 = __float2bfloat16(acc[2 * q + 1] * dv);
        const unsigned w = ((unsigned)*(const unsigned short*)&b1 << 16) |
                           *(const unsigned short*)&b0;
        ol[lane * 33 + q] = w;  // bank (lane+q)%32: 2-way, free
    }
    __syncthreads();
    unsigned* __restrict__ og = (unsigned*)(xsh + (size_t)row0 * 64);
    const int nw = nrow * 32;
    for (int i = lane; i < nw; i += 64) {  // coalesced global store
        const int r = i >> 5, q = i & 31;
        og[i] = ol[r * 33 + q];
    }
}

// Fused per-HALF-bucket sort + NODE-PAIR aggregate + epilogue. 2 blocks per
// bucket, 32 nodes each. Gather: 2 nodes per iteration, 4 chains, up to 4
// predicated uint2 loads in flight (2x per-wave MLP vs R20); quarter-lanes
// (q=lane>>4 edge slot, sl=lane&15 = dims 4sl..4sl+3). No shfl in predicated
// regions; loop bound max(degA,degB) is wave-uniform.
__global__ __launch_bounds__(256) void k_sagg(const unsigned* __restrict__ packed,
                                              const int* __restrict__ gcur,
                                              const unsigned* __restrict__ spill_pk,
                                              const unsigned* __restrict__ spill_bk,
                                              const int* __restrict__ gspill,
                                              const __hip_bfloat16* __restrict__ xsh,
                                              const float* __restrict__ bias,
                                              float* __restrict__ out) {
    __shared__ unsigned sorted[HCAP];  // 6 KB
    __shared__ int hist[32];
    __shared__ int pref[32];
    __shared__ int cur[32];
    __shared__ float sdinv[32];
    const int tid = threadIdx.x;
    const int b = blockIdx.x >> 1;         // bucket
    const unsigned half = blockIdx.x & 1;  // 0: tl 0..31, 1: tl 32..63
    int seg = gcur[b];
    seg = (seg < 0) ? 0 : (seg > CAP ? CAP : seg);
    const unsigned* __restrict__ region = packed + (size_t)b * CAP;
    int ns = *gspill;
    ns = (ns < 0) ? 0 : (ns > SPILLCAP ? SPILLCAP : ns);
    if (tid < 32) hist[tid] = 0;
    __syncthreads();
    for (int i = tid; i < seg; i += 256) {
        const unsigned pk = region[i];
        if (((pk >> 22) & 1u) == half) atomicAdd(&hist[(pk >> 17) & 31u], 1);
    }
    for (int i = tid; i < ns; i += 256) {  // spill: empty in practice
        if ((int)spill_bk[i] == b) {
            const unsigned pk = spill_pk[i];
            if (((pk >> 22) & 1u) == half) atomicAdd(&hist[(pk >> 17) & 31u], 1);
        }
    }
    __syncthreads();
    if (tid == 0) {
        int run = 0;
        for (int t = 0; t < 32; ++t) { pref[t] = run; run += hist[t]; }
    }
    __syncthreads();
    const int hcnt = pref[31] + hist[31];
    const bool oversize = (hcnt > HCAP);
    if (tid < 32) {
        cur[tid] = pref[tid];
        sdinv[tid] = rsqrtf(1.0f + (float)hist[tid]);
    }
    __syncthreads();
    if (!oversize) {
        for (int i = tid; i < seg; i += 256) {
            const unsigned pk = region[i];
            if (((pk >> 22) & 1u) == half) {
                const int pos = atomicAdd(&cur[(pk >> 17) & 31u], 1);
                if (pos < HCAP) sorted[pos] = pk & 0x1FFFFu;
            }
        }
        for (int i = tid; i < ns; i += 256) {
            if ((int)spill_bk[i] == b) {
                const unsigned pk = spill_pk[i];
                if (((pk >> 22) & 1u) == half) {
                    const int pos = atomicAdd(&cur[(pk >> 17) & 31u], 1);
                    if (pos < HCAP) sorted[pos] = pk & 0x1FFFFu;
                }
            }
        }
    }
    __syncthreads();

    const int wid = tid >> 6, lane = tid & 63;
    const int q = lane >> 4, sl = lane & 15;   // quarter, dim-quad
    const uint2* __restrict__ xs4 = (const uint2*)xsh;  // 4 bf16 per elem
    const float bv = bias[lane];
#pragma unroll 1
    for (int t = 0; t < 8; t += 2) {
        const int nlA = wid * 8 + t, nlB = nlA + 1;   // node pair
        const int cA = b * 64 + (int)half * 32 + nlA;
        const int cB = cA + 1;
        if (cA >= NN) break;               // wave-uniform
        const bool hasB = (cB < NN);       // wave-uniform
        const int offA = pref[nlA], offB = pref[nlB];
        int degA = hist[nlA];
        degA = (degA < 0) ? 0 : (degA > hcnt ? hcnt : degA);
        int degB = hasB ? hist[nlB] : 0;
        degB = (degB < 0) ? 0 : (degB > hcnt ? hcnt : degB);
        float4 a0A = {0.f,0.f,0.f,0.f}, a1A = {0.f,0.f,0.f,0.f};
        float4 a0B = {0.f,0.f,0.f,0.f}, a1B = {0.f,0.f,0.f,0.f};
        if (q == 0) {  // self-loop terms
            const uint2 vA = xs4[(size_t)cA * 16 + sl];
            UNPK4(vA, a0A)
            if (hasB) {
                const uint2 vB = xs4[(size_t)cB * 16 + sl];
                UNPK4(vB, a0B)
            }
        }
        if (!oversize) {
            const int dmax = (degA > degB) ? degA : degB;  // wave-uniform
            for (int j = 0; j < dmax; j += 8) {
                const int e0 = j + q, e1 = j + 4 + q;
                uint2 v0A = {0u,0u}, v1A = {0u,0u}, v0B = {0u,0u}, v1B = {0u,0u};
                if (e0 < degA) v0A = xs4[(size_t)sorted[offA + e0] * 16 + sl];
                if (e1 < degA) v1A = xs4[(size_t)sorted[offA + e1] * 16 + sl];
                if (e0 < degB) v0B = xs4[(size_t)sorted[offB + e0] * 16 + sl];
                if (e1 < degB) v1B = xs4[(size_t)sorted[offB + e1] * 16 + sl];
                UNPK4(v0A, a0A)
                UNPK4(v1A, a1A)
                UNPK4(v0B, a0B)
                UNPK4(v1B, a1B)
            }
        } else {  // scan-mode fallback: region + spill, tl-tagged (rare)
            if (q == 0) {
                const unsigned tlA = (unsigned)((int)half * 32 + nlA);
                const unsigned tlB = tlA + 1u;
                for (int i = 0; i < seg; ++i) {
                    const unsigned pk = region[i];
                    const unsigned tl = pk >> 17;
                    if (tl == tlA) {
                        const uint2 v = xs4[(size_t)(pk & 0x1FFFFu) * 16 + sl];
                        UNPK4(v, a0A)
                    }
                    if (hasB && tl == tlB) {
                        const uint2 v = xs4[(size_t)(pk & 0x1FFFFu) * 16 + sl];
                        UNPK4(v, a0B)
                    }
                }
                for (int i = 0; i < ns; ++i) {
                    if ((int)spill_bk[i] == b) {
                        const unsigned pk = spill_pk[i];
                        const unsigned tl = pk >> 17;
                        if (tl == tlA) {
                            const uint2 v = xs4[(size_t)(pk & 0x1FFFFu) * 16 + sl];
                            UNPK4(v, a0A)
                        }
                        if (hasB && tl == tlB) {
                            const uint2 v = xs4[(size_t)(pk & 0x1FFFFu) * 16 + sl];
                            UNPK4(v, a0B)
                        }
                    }
                }
            }
        }
        sagg_finish(a0A, a1A, lane, cA, sdinv[nlA], bv, out);
        if (hasB) sagg_finish(a0B, a1B, lane, cB, sdinv[nlB], bv, out);
    }
}

extern "C" void kernel_launch(void* const* d_in, const int* in_sizes, int n_in,
                              void* d_out, int out_size, void* d_ws, size_t ws_size,
                              hipStream_t stream) {
    const float* x  = (const float*)d_in[0];
    const float* W  = (const float*)d_in[1];
    const float* b  = (const float*)d_in[2];
    const int*   ei = (const int*)d_in[3];
    float* out = (float*)d_out;

    __hip_bfloat16* xsh = (__hip_bfloat16*)d_ws;              // bf16[NN*64]
    unsigned* packed = (unsigned*)(xsh + (size_t)NN * 64);    // u32[NBUCK*CAP]
    int* gcur = (int*)(packed + (size_t)NBUCK * CAP);         // i32[NBUCK]
    int* gspill = gcur + NBUCK;                               // i32[1]
    unsigned* spill_pk = (unsigned*)(gspill + 1);             // u32[SPILLCAP]
    unsigned* spill_bk = spill_pk + SPILLCAP;                 // u32[SPILLCAP]

    hipMemsetAsync(gcur, 0, (NBUCK + 1) * sizeof(int), stream);
    k_p1<<<P1B, P1T, 0, stream>>>(ei, gcur, packed, spill_pk, spill_bk, gspill);
    k_xw<<<NBUCK, 64, 0, stream>>>(x, W, packed, gcur, spill_pk, spill_bk, gspill, xsh);
    k_sagg<<<NBUCK * 2, 256, 0, stream>>>(packed, gcur, spill_pk, spill_bk, gspill, xsh, b, out);
}

// Round 22
// 115.664 us; speedup vs baseline: 1.6348x; 1.0095x over previous
//
#include <hip/hip_runtime.h>
#include <hip/hip_bf16.h>

// GCNConv: one-pass fixed-capacity binning (64 tgts/bucket, CAP slots each) ->
// fused per-half-bucket {LDS counting sort + node-pair quarter-lane gather +
// epilogue}. No fp32 global atomics anywhere.
// agg[c] = dinv[c] * ( xs[c] + sum_{e: col[e]==c} xs[row[e]] ),
//   xs[i] = (x@W)[i] * dinv[i],  dinv[i] = rsqrt(1 + indeg(i))
// out = dropout(tanh(agg + b)), JAX partitionable-threefry key (0,42), p_keep=0.9:
//   bits[p] = o0^o1 of threefry((0,42), 0, p); u = bitcast(bits>>9|0x3f800000)-1; keep = u<0.9.
//
// R8: __shfl only in uniform regions (predicated regions contain loads only).
// R21: node-pair gather (4 loads in flight) -> sagg 57us, total 116.8us.
// R22: k_xw persists its per-bucket hist to deg[NN]; k_sagg loads deg with one
//   coalesced read instead of re-scanning its segment (one full region pass +
//   1.6M LDS atomics + a barrier phase deleted). CAP 1216->1152 to keep ws
//   at 20.5MB (spill path absorbs the rare +4sigma bucket overflow).
//
// ws (~20.5 MB): xsh bf16[NN*64] | packed u32[NBUCK*CAP] | gcur i32[NBUCK] |
//                gspill i32[1] | spill_pk u32[SPILLCAP] | spill_bk u32[SPILLCAP] |
//                deg i32[NN]

#define NN 100000
#define NE 1600000
#define NBUCK 1563
#define P1B 256
#define P1T 1024
#define CHUNK 6250          // P1B * CHUNK == NE
#define CAP 1152            // per-bucket region (mean 1024, +4 sigma; spill covers rest)
#define SPILLCAP 16384
#define HCAP 1536           // per-half-bucket LDS sort capacity

// ---------------- Threefry2x32 (JAX-exact) ----------------
__device__ __forceinline__ unsigned rotl32(unsigned x, int r) {
    return (x << r) | (x >> (32 - r));
}

__device__ __forceinline__ void threefry2x32(unsigned k0, unsigned k1,
                                             unsigned x0, unsigned x1,
                                             unsigned& o0, unsigned& o1) {
    const unsigned ks0 = k0, ks1 = k1, ks2 = k0 ^ k1 ^ 0x1BD11BDAu;
    x0 += ks0; x1 += ks1;
    x0 += x1; x1 = rotl32(x1, 13); x1 ^= x0;
    x0 += x1; x1 = rotl32(x1, 15); x1 ^= x0;
    x0 += x1; x1 = rotl32(x1, 26); x1 ^= x0;
    x0 += x1; x1 = rotl32(x1, 6);  x1 ^= x0;
    x0 += ks1; x1 += ks2 + 1u;
    x0 += x1; x1 = rotl32(x1, 17); x1 ^= x0;
    x0 += x1; x1 = rotl32(x1, 29); x1 ^= x0;
    x0 += x1; x1 = rotl32(x1, 16); x1 ^= x0;
    x0 += x1; x1 = rotl32(x1, 24); x1 ^= x0;
    x0 += ks2; x1 += ks0 + 2u;
    x0 += x1; x1 = rotl32(x1, 13); x1 ^= x0;
    x0 += x1; x1 = rotl32(x1, 15); x1 ^= x0;
    x0 += x1; x1 = rotl32(x1, 26); x1 ^= x0;
    x0 += x1; x1 = rotl32(x1, 6);  x1 ^= x0;
    x0 += ks0; x1 += ks1 + 3u;
    x0 += x1; x1 = rotl32(x1, 17); x1 ^= x0;
    x0 += x1; x1 = rotl32(x1, 29); x1 ^= x0;
    x0 += x1; x1 = rotl32(x1, 16); x1 ^= x0;
    x0 += x1; x1 = rotl32(x1, 24); x1 ^= x0;
    x0 += ks1; x1 += ks2 + 4u;
    x0 += x1; x1 = rotl32(x1, 13); x1 ^= x0;
    x0 += x1; x1 = rotl32(x1, 15); x1 ^= x0;
    x0 += x1; x1 = rotl32(x1, 26); x1 ^= x0;
    x0 += x1; x1 = rotl32(x1, 6);  x1 ^= x0;
    x0 += ks2; x1 += ks0 + 5u;
    o0 = x0; o1 = x1;
}

// Per-node epilogue: quarter-reduce, redistribute, tanh + threefry dropout.
// Contains shfls — call ONLY under wave-uniform control flow.
__device__ __forceinline__ void sagg_finish(float4 a0, float4 a1, int lane,
                                            int c, float dv, float bv,
                                            float* __restrict__ out) {
    float ax = a0.x + a1.x, ay = a0.y + a1.y;
    float az = a0.z + a1.z, aw = a0.w + a1.w;
    ax += __shfl_xor(ax, 16); ax += __shfl_xor(ax, 32);
    ay += __shfl_xor(ay, 16); ay += __shfl_xor(ay, 32);
    az += __shfl_xor(az, 16); az += __shfl_xor(az, 32);
    aw += __shfl_xor(aw, 16); aw += __shfl_xor(aw, 32);
    const float sx = __shfl(ax, lane >> 2);
    const float sy = __shfl(ay, lane >> 2);
    const float sz = __shfl(az, lane >> 2);
    const float sw = __shfl(aw, lane >> 2);
    const float ab = (lane & 1) ? sy : sx;
    const float cd = (lane & 1) ? sw : sz;
    const float a = (lane & 2) ? cd : ab;
    const int p = c * 64 + lane;
    unsigned o0, o1;
    threefry2x32(0u, 42u, 0u, (unsigned)p, o0, o1);
    const unsigned bits = o0 ^ o1;
    const float u = __uint_as_float((bits >> 9) | 0x3f800000u) - 1.0f;
    const float h = tanhf(dv * a + bv);
    out[p] = (u < 0.9f) ? h / 0.9f : 0.0f;
}

#define UNPK4(v, A)                                                    \
    A.x += __uint_as_float((v).x << 16);                               \
    A.y += __uint_as_float((v).x & 0xffff0000u);                       \
    A.z += __uint_as_float((v).y << 16);                               \
    A.w += __uint_as_float((v).y & 0xffff0000u);

// ---------------- Kernels ----------------
// One-pass binning: LDS hist -> one global reserve atomic per (block,bucket)
// -> grouped writes into fixed regions. Overflow -> spill list.
__global__ __launch_bounds__(P1T) void k_p1(const int* __restrict__ ei,
                                            int* __restrict__ gcur,
                                            unsigned* __restrict__ packed,
                                            unsigned* __restrict__ spill_pk,
                                            unsigned* __restrict__ spill_bk,
                                            int* __restrict__ gspill) {
    __shared__ int hb[NBUCK];
    __shared__ int lc[NBUCK];
    const int tid = threadIdx.x;
    for (int i = tid; i < NBUCK; i += P1T) { hb[i] = 0; lc[i] = 0; }
    __syncthreads();
    const int base = blockIdx.x * CHUNK;
    for (int i = tid; i < CHUNK; i += P1T) {
        const unsigned t = (unsigned)ei[NE + base + i];
        if (t < NN) atomicAdd(&hb[t >> 6], 1);
    }
    __syncthreads();
    for (int i = tid; i < NBUCK; i += P1T) {
        const int h = hb[i];
        hb[i] = h ? atomicAdd(&gcur[i], h) : 0;  // reserve (may exceed CAP)
        lc[i] = 0;
    }
    __syncthreads();
    for (int i = tid; i < CHUNK; i += P1T) {
        const unsigned t = (unsigned)ei[NE + base + i];
        if (t >= NN) continue;
        const unsigned src = (unsigned)ei[base + i];
        const int bk = t >> 6;
        const unsigned pk = src | ((t & 63u) << 17);
        const int pos = hb[bk] + atomicAdd(&lc[bk], 1);
        if (pos < CAP) {
            packed[(size_t)bk * CAP + pos] = pk;
        } else {  // rare overflow: graceful spill
            const int sp = atomicAdd(gspill, 1);
            if (sp < SPILLCAP) { spill_pk[sp] = pk; spill_bk[sp] = (unsigned)bk; }
        }
    }
}

// x@W, lane=row: one 64-thread wave per bucket (64 rows). x staged in padded
// LDS [64][65]; W via wave-uniform scalar loads (s_load + SGPR-operand FMA).
// deg hist fused (region + spill) and PERSISTED to deg_g for k_sagg.
__global__ __launch_bounds__(64) void k_xw(const float* __restrict__ x,
                                           const float* __restrict__ W,
                                           const unsigned* __restrict__ packed,
                                           const int* __restrict__ gcur,
                                           const unsigned* __restrict__ spill_pk,
                                           const unsigned* __restrict__ spill_bk,
                                           const int* __restrict__ gspill,
                                           int* __restrict__ deg_g,
                                           __hip_bfloat16* __restrict__ xsh) {
    __shared__ float xl[64 * 65];   // 16.64 KB (reused as out-bounce)
    __shared__ int hist[64];
    const int lane = threadIdx.x;   // block == 1 wave; lane == local row
    const int b = blockIdx.x;       // bucket; rows [64b, 64b+64)
    const int row0 = b * 64;
    const int nrow = (NN - row0) < 64 ? (NN - row0) : 64;
    {   // stage x rows, coalesced float4; LDS row stride 65 floats
        const float4* __restrict__ xg = (const float4*)(x + (size_t)row0 * 64);
        const int nf4 = nrow * 16;
        for (int i = lane; i < nf4; i += 64) {
            const int r = i >> 4, q = i & 15;
            *(float4*)&xl[r * 65 + 4 * q] = xg[i];
        }
    }
    hist[lane] = 0;
    __syncthreads();
    {   // degree hist: fixed region + spill (spill empty in practice)
        int cnt = gcur[b];
        cnt = (cnt < 0) ? 0 : (cnt > CAP ? CAP : cnt);
        const unsigned* __restrict__ seg = packed + (size_t)b * CAP;
        for (int i = lane; i < cnt; i += 64) atomicAdd(&hist[seg[i] >> 17], 1);
        int ns = *gspill;
        ns = (ns < 0) ? 0 : (ns > SPILLCAP ? SPILLCAP : ns);
        for (int i = lane; i < ns; i += 64)
            if ((int)spill_bk[i] == b) atomicAdd(&hist[(spill_pk[i] >> 17) & 63u], 1);
    }
    __syncthreads();
    const int myrow = row0 + lane;
    if (myrow < NN) deg_g[myrow] = hist[lane];  // persist for k_sagg
    const float dv = rsqrtf(1.0f + (float)hist[lane]);  // this lane's row
    float acc[64];
#pragma unroll
    for (int d = 0; d < 64; ++d) acc[d] = 0.0f;
#pragma unroll 1
    for (int k = 0; k < 64; ++k) {
        const float xv = xl[lane * 65 + k];  // per-lane, (lane+k)%32 banks
#pragma unroll
        for (int d = 0; d < 64; ++d)         // W[k*64+d] is wave-uniform ->
            acc[d] = fmaf(xv, W[k * 64 + d], acc[d]);  // s_load + SGPR FMA
    }
    __syncthreads();  // xl reuse as bounce buffer
    unsigned* __restrict__ ol = (unsigned*)xl;  // [64][33] packed bf16 pairs
#pragma unroll
    for (int q = 0; q < 32; ++q) {
        const __hip_bfloat16 b0 = __float2bfloat16(acc[2 * q] * dv);
        const __hip_bfloat16 b1 = __float2bfloat16(acc[2 * q + 1] * dv);
        const unsigned w = ((unsigned)*(const unsigned short*)&b1 << 16) |
                           *(const unsigned short*)&b0;
        ol[lane * 33 + q] = w;  // bank (lane+q)%32: 2-way, free
    }
    __syncthreads();
    unsigned* __restrict__ og = (unsigned*)(xsh + (size_t)row0 * 64);
    const int nw = nrow * 32;
    for (int i = lane; i < nw; i += 64) {  // coalesced global store
        const int r = i >> 5, q = i & 31;
        og[i] = ol[r * 33 + q];
    }
}

// Fused per-HALF-bucket sort + NODE-PAIR aggregate + epilogue. Degrees come
// from deg_g (one coalesced read) — no hist scan. 2 blocks/bucket, 32 nodes.
// Gather: 2 nodes/iter, 4 chains, 4 predicated uint2 loads in flight.
__global__ __launch_bounds__(256) void k_sagg(const unsigned* __restrict__ packed,
                                              const int* __restrict__ gcur,
                                              const unsigned* __restrict__ spill_pk,
                                              const unsigned* __restrict__ spill_bk,
                                              const int* __restrict__ gspill,
                                              const int* __restrict__ deg_g,
                                              const __hip_bfloat16* __restrict__ xsh,
                                              const float* __restrict__ bias,
                                              float* __restrict__ out) {
    __shared__ unsigned sorted[HCAP];  // 6 KB
    __shared__ int hist[32];
    __shared__ int pref[32];
    __shared__ int cur[32];
    __shared__ float sdinv[32];
    const int tid = threadIdx.x;
    const int b = blockIdx.x >> 1;         // bucket
    const unsigned half = blockIdx.x & 1;  // 0: tl 0..31, 1: tl 32..63
    int seg = gcur[b];
    seg = (seg < 0) ? 0 : (seg > CAP ? CAP : seg);
    const unsigned* __restrict__ region = packed + (size_t)b * CAP;
    int ns = *gspill;
    ns = (ns < 0) ? 0 : (ns > SPILLCAP ? SPILLCAP : ns);
    if (tid < 32) {  // degrees from k_xw (includes spill) — no region scan
        const int c = b * 64 + (int)half * 32 + tid;
        hist[tid] = (c < NN) ? deg_g[c] : 0;
    }
    __syncthreads();
    if (tid == 0) {
        int run = 0;
        for (int t = 0; t < 32; ++t) { pref[t] = run; run += hist[t]; }
    }
    __syncthreads();
    const int hcnt = pref[31] + hist[31];
    const bool oversize = (hcnt > HCAP);
    if (tid < 32) {
        cur[tid] = pref[tid];
        sdinv[tid] = rsqrtf(1.0f + (float)hist[tid]);
    }
    __syncthreads();
    if (!oversize) {
        for (int i = tid; i < seg; i += 256) {
            const unsigned pk = region[i];
            if (((pk >> 22) & 1u) == half) {
                const int pos = atomicAdd(&cur[(pk >> 17) & 31u], 1);
                if (pos < HCAP) sorted[pos] = pk & 0x1FFFFu;
            }
        }
        for (int i = tid; i < ns; i += 256) {  // spill: empty in practice
            if ((int)spill_bk[i] == b) {
                const unsigned pk = spill_pk[i];
                if (((pk >> 22) & 1u) == half) {
                    const int pos = atomicAdd(&cur[(pk >> 17) & 31u], 1);
                    if (pos < HCAP) sorted[pos] = pk & 0x1FFFFu;
                }
            }
        }
    }
    __syncthreads();

    const int wid = tid >> 6, lane = tid & 63;
    const int q = lane >> 4, sl = lane & 15;   // quarter, dim-quad
    const uint2* __restrict__ xs4 = (const uint2*)xsh;  // 4 bf16 per elem
    const float bv = bias[lane];
#pragma unroll 1
    for (int t = 0; t < 8; t += 2) {
        const int nlA = wid * 8 + t, nlB = nlA + 1;   // node pair
        const int cA = b * 64 + (int)half * 32 + nlA;
        const int cB = cA + 1;
        if (cA >= NN) break;               // wave-uniform
        const bool hasB = (cB < NN);       // wave-uniform
        const int offA = pref[nlA], offB = pref[nlB];
        int degA = hist[nlA];
        degA = (degA < 0) ? 0 : (degA > hcnt ? hcnt : degA);
        int degB = hasB ? hist[nlB] : 0;
        degB = (degB < 0) ? 0 : (degB > hcnt ? hcnt : degB);
        float4 a0A = {0.f,0.f,0.f,0.f}, a1A = {0.f,0.f,0.f,0.f};
        float4 a0B = {0.f,0.f,0.f,0.f}, a1B = {0.f,0.f,0.f,0.f};
        if (q == 0) {  // self-loop terms
            const uint2 vA = xs4[(size_t)cA * 16 + sl];
            UNPK4(vA, a0A)
            if (hasB) {
                const uint2 vB = xs4[(size_t)cB * 16 + sl];
                UNPK4(vB, a0B)
            }
        }
        if (!oversize) {
            const int dmax = (degA > degB) ? degA : degB;  // wave-uniform
            for (int j = 0; j < dmax; j += 8) {
                const int e0 = j + q, e1 = j + 4 + q;
                uint2 v0A = {0u,0u}, v1A = {0u,0u}, v0B = {0u,0u}, v1B = {0u,0u};
                if (e0 < degA) v0A = xs4[(size_t)sorted[offA + e0] * 16 + sl];
                if (e1 < degA) v1A = xs4[(size_t)sorted[offA + e1] * 16 + sl];
                if (e0 < degB) v0B = xs4[(size_t)sorted[offB + e0] * 16 + sl];
                if (e1 < degB) v1B = xs4[(size_t)sorted[offB + e1] * 16 + sl];
                UNPK4(v0A, a0A)
                UNPK4(v1A, a1A)
                UNPK4(v0B, a0B)
                UNPK4(v1B, a1B)
            }
        } else {  // scan-mode fallback: region + spill, tl-tagged (rare)
            if (q == 0) {
                const unsigned tlA = (unsigned)((int)half * 32 + nlA);
                const unsigned tlB = tlA + 1u;
                for (int i = 0; i < seg; ++i) {
                    const unsigned pk = region[i];
                    const unsigned tl = pk >> 17;
                    if (tl == tlA) {
                        const uint2 v = xs4[(size_t)(pk & 0x1FFFFu) * 16 + sl];
                        UNPK4(v, a0A)
                    }
                    if (hasB && tl == tlB) {
                        const uint2 v = xs4[(size_t)(pk & 0x1FFFFu) * 16 + sl];
                        UNPK4(v, a0B)
                    }
                }
                for (int i = 0; i < ns; ++i) {
                    if ((int)spill_bk[i] == b) {
                        const unsigned pk = spill_pk[i];
                        const unsigned tl = pk >> 17;
                        if (tl == tlA) {
                            const uint2 v = xs4[(size_t)(pk & 0x1FFFFu) * 16 + sl];
                            UNPK4(v, a0A)
                        }
                        if (hasB && tl == tlB) {
                            const uint2 v = xs4[(size_t)(pk & 0x1FFFFu) * 16 + sl];
                            UNPK4(v, a0B)
                        }
                    }
                }
            }
        }
        sagg_finish(a0A, a1A, lane, cA, sdinv[nlA], bv, out);
        if (hasB) sagg_finish(a0B, a1B, lane, cB, sdinv[nlB], bv, out);
    }
}

extern "C" void kernel_launch(void* const* d_in, const int* in_sizes, int n_in,
                              void* d_out, int out_size, void* d_ws, size_t ws_size,
                              hipStream_t stream) {
    const float* x  = (const float*)d_in[0];
    const float* W  = (const float*)d_in[1];
    const float* b  = (const float*)d_in[2];
    const int*   ei = (const int*)d_in[3];
    float* out = (float*)d_out;

    __hip_bfloat16* xsh = (__hip_bfloat16*)d_ws;              // bf16[NN*64]
    unsigned* packed = (unsigned*)(xsh + (size_t)NN * 64);    // u32[NBUCK*CAP]
    int* gcur = (int*)(packed + (size_t)NBUCK * CAP);         // i32[NBUCK]
    int* gspill = gcur + NBUCK;                               // i32[1]
    unsigned* spill_pk = (unsigned*)(gspill + 1);             // u32[SPILLCAP]
    unsigned* spill_bk = spill_pk + SPILLCAP;                 // u32[SPILLCAP]
    int* deg_g = (int*)(spill_bk + SPILLCAP);                 // i32[NN]

    hipMemsetAsync(gcur, 0, (NBUCK + 1) * sizeof(int), stream);
    k_p1<<<P1B, P1T, 0, stream>>>(ei, gcur, packed, spill_pk, spill_bk, gspill);
    k_xw<<<NBUCK, 64, 0, stream>>>(x, W, packed, gcur, spill_pk, spill_bk, gspill, deg_g, xsh);
    k_sagg<<<NBUCK * 2, 256, 0, stream>>>(packed, gcur, spill_pk, spill_bk, gspill, deg_g, xsh, b, out);
}